// Round 15
// baseline (945.049 us; speedup 1.0000x reference)
//
#include <hip/hip_runtime.h>
#include <hip/hip_bf16.h>
#include <cstdint>

#define NN 50000
#define EE 800000
#define RR 8
#define GG 128
#define D0 384
#define DL 256

typedef __attribute__((ext_vector_type(8))) short bf16x8;
typedef __attribute__((ext_vector_type(4))) float f32x4;

__device__ __forceinline__ float sigmoidf_(float x) { return 1.0f / (1.0f + expf(-x)); }

__device__ __forceinline__ ushort f2bf(float f) {
    uint u = __float_as_uint(f);
    u += 0x7fffu + ((u >> 16) & 1u);
    return (ushort)(u >> 16);
}
__device__ __forceinline__ uint pack2bf(float lo, float hi) {
    return (uint)f2bf(lo) | ((uint)f2bf(hi) << 16);
}
__device__ __forceinline__ float bf2f(ushort u) {
    return __uint_as_float((uint)u << 16);
}

// ---- fp8 e4m3fn (OCP), manual RNE + saturate; self-consistent encode/decode ----
__device__ __forceinline__ unsigned char f2fp8(float x) {
    uint s = (__float_as_uint(x) >> 24) & 0x80u;
    float a = fabsf(x);
    if (a >= 448.f) return (unsigned char)(s | 0x7Eu);
    if (a < 0.015625f) {                    // subnormal: q * 2^-9 (q==8 -> 0x08 == 2^-6 normal)
        int q = (int)rintf(a * 512.0f);
        return (unsigned char)(s | (uint)q);
    }
    uint b = __float_as_uint(a);
    b += 0x7FFFFu + ((b >> 20) & 1u);       // RNE to 3 mantissa bits
    int e = (int)(b >> 23) - 120;           // biased e4m3 exponent
    uint m = (b >> 20) & 7u;
    if (e > 15 || (e == 15 && m == 7u)) return (unsigned char)(s | 0x7Eu);
    return (unsigned char)(s | ((uint)e << 3) | m);
}
__device__ __forceinline__ float fp8d(uint b) {
    uint s = (b & 0x80u) << 24;
    uint e = (b >> 3) & 15u;
    uint m = b & 7u;
    float v = e ? __uint_as_float(((e + 120u) << 23) | (m << 20))
                : (float)m * 0.001953125f;  // m * 2^-9
    return __uint_as_float(__float_as_uint(v) | s);
}
// acc[0..7] += w * 8 x fp8
__device__ __forceinline__ void accf8(float* s, uint2 a, float w) {
    #pragma unroll
    for (int q = 0; q < 4; q++) s[q]     += w * fp8d((a.x >> (8 * q)) & 0xffu);
    #pragma unroll
    for (int q = 0; q < 4; q++) s[4 + q] += w * fp8d((a.y >> (8 * q)) & 0xffu);
}

// unpack 8 bf16 to fp32
__device__ __forceinline__ void unp8(float* f, uint4 a) {
    f[0] = __uint_as_float(a.x << 16);
    f[1] = __uint_as_float(a.x & 0xffff0000u);
    f[2] = __uint_as_float(a.y << 16);
    f[3] = __uint_as_float(a.y & 0xffff0000u);
    f[4] = __uint_as_float(a.z << 16);
    f[5] = __uint_as_float(a.z & 0xffff0000u);
    f[6] = __uint_as_float(a.w << 16);
    f[7] = __uint_as_float(a.w & 0xffff0000u);
}
__device__ __forceinline__ uint4 pack8bf(const float* f) {
    uint4 p;
    p.x = pack2bf(f[0], f[1]);
    p.y = pack2bf(f[2], f[3]);
    p.z = pack2bf(f[4], f[5]);
    p.w = pack2bf(f[6], f[7]);
    return p;
}
// acc[0..7] += w * bf16x8(v)
__device__ __forceinline__ void accw8(float* s, uint4 a, float w) {
    s[0] += w * __uint_as_float(a.x << 16);
    s[1] += w * __uint_as_float(a.x & 0xffff0000u);
    s[2] += w * __uint_as_float(a.y << 16);
    s[3] += w * __uint_as_float(a.y & 0xffff0000u);
    s[4] += w * __uint_as_float(a.z << 16);
    s[5] += w * __uint_as_float(a.z & 0xffff0000u);
    s[6] += w * __uint_as_float(a.w << 16);
    s[7] += w * __uint_as_float(a.w & 0xffff0000u);
}

// order-preserving float->uint encoding for atomicMax
__device__ __forceinline__ unsigned fenc(float x) {
    unsigned u = __float_as_uint(x);
    return (u & 0x80000000u) ? ~u : (u | 0x80000000u);
}
__device__ __forceinline__ float fdec(unsigned u) {
    unsigned b = (u & 0x80000000u) ? (u & 0x7fffffffu) : ~u;
    return __uint_as_float(b);
}

// ---------------- embedding concat: h0[n, 0:384] (bf16) ----------------
__global__ __launch_bounds__(256) void embed_kernel(
    const int* __restrict__ x,
    const float* __restrict__ e0, const float* __restrict__ e1,
    const float* __restrict__ e2, const float* __restrict__ e3,
    const float* __restrict__ e4, const float* __restrict__ e5,
    ushort* __restrict__ h0)
{
    int idx = blockIdx.x * 256 + threadIdx.x;   // over NN*48 8-elem chunks
    if (idx >= NN * 48) return;
    int n = idx / 48;
    int q = idx - n * 48;
    int d = q * 8;
    int tbl = d >> 6;
    int w = d & 63;
    int row = x[n * 6 + tbl];
    const float* src;
    switch (tbl) {
        case 0: src = e0; break; case 1: src = e1; break; case 2: src = e2; break;
        case 3: src = e3; break; case 4: src = e4; break; default: src = e5; break;
    }
    float4 f0 = *(const float4*)&src[row * 64 + w];
    float4 f1 = *(const float4*)&src[row * 64 + w + 4];
    uint4 pk;
    pk.x = pack2bf(f0.x, f0.y);
    pk.y = pack2bf(f0.z, f0.w);
    pk.z = pack2bf(f1.x, f1.y);
    pk.w = pack2bf(f1.z, f1.w);
    *(uint4*)&h0[(size_t)n * D0 + d] = pk;
}

// ---------------- weight convert + transpose: WbT[r*256+n][k] = bf16(W[r][k][n]) ----------------
__global__ __launch_bounds__(256) void cvtT_kernel(
    const float* __restrict__ W, const float* __restrict__ root,
    ushort* __restrict__ WbT, int nrel, int IN)
{
    int idx = blockIdx.x * 256 + threadIdx.x;
    int tot = (nrel + 1) * DL * IN;
    if (idx >= tot) return;
    int k = idx % IN;
    int rn = idx / IN;
    int n = rn % DL;
    int r = rn / DL;
    float v = (r < nrel) ? W[((size_t)r * IN + k) * DL + n] : root[(size_t)k * DL + n];
    WbT[idx] = f2bf(v);
}

// ---------------- CSR build ----------------
__global__ __launch_bounds__(256) void count_kernel(
    const int* __restrict__ dst, const int* __restrict__ et, int* __restrict__ counts)
{
    int i = blockIdx.x * 256 + threadIdx.x;
    if (i < EE) atomicAdd(&counts[dst[i] * RR + et[i]], 1);
}

#define SCAN_CHUNK 4096
__global__ __launch_bounds__(256) void scanA_kernel(const int* __restrict__ cnt, int M, int* __restrict__ blkSums)
{
    __shared__ int s[256];
    int b = blockIdx.x, t = threadIdx.x;
    int base = b * SCAN_CHUNK + t * 16;
    int tot = 0;
    #pragma unroll
    for (int i = 0; i < 16; i++) { int idx = base + i; if (idx < M) tot += cnt[idx]; }
    s[t] = tot; __syncthreads();
    for (int off = 128; off > 0; off >>= 1) {
        if (t < off) s[t] += s[t + off];
        __syncthreads();
    }
    if (t == 0) blkSums[b] = s[0];
}

// wave-parallel exclusive scan over NB<=128 block sums (was a serial 1-thread loop ~20us)
__global__ void scanB_kernel(const int* __restrict__ blkSums, int NB, int* __restrict__ blkOff)
{
    int l = threadIdx.x;              // 64 lanes
    int a = (l < NB) ? blkSums[l] : 0;
    int b = (64 + l < NB) ? blkSums[64 + l] : 0;
    int ia = a, ib = b;
    for (int o = 1; o < 64; o <<= 1) {
        int t0 = __shfl_up(ia, o, 64);
        if (l >= o) ia += t0;
        int t1 = __shfl_up(ib, o, 64);
        if (l >= o) ib += t1;
    }
    int tot0 = __shfl(ia, 63, 64);
    if (l < NB) blkOff[l] = ia - a;
    if (64 + l < NB) blkOff[64 + l] = tot0 + ib - b;
}

__global__ __launch_bounds__(256) void scanC_kernel(
    const int* __restrict__ cnt, int M, const int* __restrict__ blkOff,
    int* __restrict__ offs, int* __restrict__ curs)
{
    __shared__ int s[256];
    int b = blockIdx.x, t = threadIdx.x;
    int base = b * SCAN_CHUNK + t * 16;
    int loc[16];
    int tot = 0;
    #pragma unroll
    for (int i = 0; i < 16; i++) {
        int idx = base + i;
        int v = (idx < M) ? cnt[idx] : 0;
        loc[i] = tot; tot += v;
    }
    s[t] = tot; __syncthreads();
    for (int off = 1; off < 256; off <<= 1) {
        int v = (t >= off) ? s[t - off] : 0;
        __syncthreads();
        s[t] += v;
        __syncthreads();
    }
    int texc = s[t] - tot;           // exclusive prefix of this thread
    int bb = blkOff[b];
    #pragma unroll
    for (int i = 0; i < 16; i++) {
        int idx = base + i;
        if (idx < M) { int o = bb + texc + loc[i]; offs[idx] = o; curs[idx] = o; }
    }
}

// scatter: per-edge gather index into the npc-relation chunk (fp8 element units)
// eidx = src*chc + (r & (npc-1))*256 ; weight 1/cnt.
__global__ __launch_bounds__(256) void scatter_kernel(
    const int* __restrict__ src, const int* __restrict__ dst, const int* __restrict__ et,
    const int* __restrict__ cnts, int* __restrict__ cursors,
    int* __restrict__ eidx, float* __restrict__ ew, int chc, int mask)
{
    int i = blockIdx.x * 256 + threadIdx.x;
    if (i < EE) {
        int r = et[i];
        int b = dst[i] * RR + r;
        int pos = atomicAdd(&cursors[b], 1);
        eidx[pos] = src[i] * chc + (r & mask) * DL;
        ew[pos] = 1.0f / (float)cnts[b];
    }
}

// ---------------- dense bf16 MFMA GEMM: frag-packed double-buffered LDS (R14) ----
// Tile BM=128 x BN=128 x BK=64, 4 waves. Frag-packed XOR-swizzled LDS, true
// double buffer (64KB), one barrier/K-tile, pinned prefetch (sched_barrier),
// T1 bijective XCD remap. MODE 0: write fp8 messages (halves hr bytes);
// MODE 1: +bias, write bf16 (gate); MODE 2: +hacc(bf16)+bias+sigmoid, bf16.
template<int K, int MODE>
__global__ __launch_bounds__(256) void dense_gemm(
    const ushort* __restrict__ A,    // [M][K] bf16
    const ushort* __restrict__ Bt,   // [NCOL][K] bf16 (rows = C cols)
    const float* __restrict__ bias,  // [NCOL] (MODE>=1)
    const ushort* __restrict__ haccp,// [M][256] bf16 (MODE==2)
    void* __restrict__ Cv,           // MODE0: fp8 [M][NCOL]; else bf16
    int M, int NCOL)
{
    constexpr int NKT = K / 64;
    __shared__ __attribute__((aligned(16))) ushort Al[2][128 * 64];  // 2x16 KB
    __shared__ __attribute__((aligned(16))) ushort Bl[2][128 * 64];  // 2x16 KB

    // ---- T1: bijective XCD-chunked remap (m204) ----
    const int nwg  = gridDim.x * gridDim.y;
    const int flat = blockIdx.y * gridDim.x + blockIdx.x;
    const int q8 = nwg >> 3, r8 = nwg & 7;
    const int xcd = flat & 7, pos = flat >> 3;
    const int vid = ((xcd < r8) ? xcd * (q8 + 1) : r8 * (q8 + 1) + (xcd - r8) * q8) + pos;
    const int m0  = (vid / gridDim.x) * 128;
    const int n0  = (vid % gridDim.x) * 128;

    const int t    = threadIdx.x;
    const int lane = t & 63;
    const int wv   = t >> 6;
    const int wr   = (wv >> 1) * 64;  // wave row offset
    const int wc   = (wv & 1) * 64;   // wave col offset
    const int l15  = lane & 15;
    const int kg   = lane >> 4;

    // staging decomposition: thread covers rows sr+32i, global elems [sc, sc+8)
    const int sr = t >> 3;
    const int sc = (t & 7) * 8;
    const int g0 = sc,      g1 = sc + 4;
    const int s0 = ((g0 >> 5) << 2) + ((g0 & 15) >> 2), h0_ = (g0 >> 4) & 1;
    const int s1 = ((g1 >> 5) << 2) + ((g1 & 15) >> 2), h1_ = (g1 >> 4) & 1;

    int arow[4], brow[4];
    #pragma unroll
    for (int i = 0; i < 4; i++) {
        int r = sr + i * 32;
        arow[i] = min(m0 + r, M - 1);
        brow[i] = n0 + r;
    }

    uint4 av[4], bv[4];
    auto SLOAD = [&](int kt) {
        const ushort* Ak = A + kt * 64 + sc;
        const ushort* Bk = Bt + kt * 64 + sc;
        #pragma unroll
        for (int i = 0; i < 4; i++) av[i] = *(const uint4*)(Ak + (size_t)arow[i] * K);
        #pragma unroll
        for (int i = 0; i < 4; i++) bv[i] = *(const uint4*)(Bk + (size_t)brow[i] * K);
    };
    auto SWRITE = [&](int buf) {
        #pragma unroll
        for (int i = 0; i < 4; i++) {
            int row = sr + i * 32;
            int rx  = row & 7;
            int o0  = row * 64 + (((s0 ^ rx) << 3) + h0_ * 4);
            int o1  = row * 64 + (((s1 ^ rx) << 3) + h1_ * 4);
            *(uint2*)&Al[buf][o0] = make_uint2(av[i].x, av[i].y);
            *(uint2*)&Al[buf][o1] = make_uint2(av[i].z, av[i].w);
            *(uint2*)&Bl[buf][o0] = make_uint2(bv[i].x, bv[i].y);
            *(uint2*)&Bl[buf][o1] = make_uint2(bv[i].z, bv[i].w);
        }
    };

    f32x4 acc[4][4];
    #pragma unroll
    for (int mt = 0; mt < 4; mt++)
        #pragma unroll
        for (int nt = 0; nt < 4; nt++) acc[mt][nt] = (f32x4){0.f, 0.f, 0.f, 0.f};

    union FR { bf16x8 v; uint u[4]; };

    SLOAD(0);
    SWRITE(0);
    __syncthreads();

    for (int kt = 0; kt < NKT; kt++) {
        const int cur = kt & 1;
        if (kt + 1 < NKT) {
            SLOAD(kt + 1);                       // issue prefetch...
            __builtin_amdgcn_sched_barrier(0);   // ...pinned before the MFMA phase
        }
        const ushort* Ap = Al[cur];
        const ushort* Bp = Bl[cur];
        #pragma unroll
        for (int kb = 0; kb < 2; kb++) {
            const int s = kb * 4 + kg;
            FR a[4], b[4];
            #pragma unroll
            for (int mt = 0; mt < 4; mt++) {
                int row = wr + mt * 16 + l15;
                uint4 va = *(const uint4*)&Ap[row * 64 + ((s ^ (row & 7)) << 3)];
                a[mt].u[0] = va.x; a[mt].u[1] = va.y; a[mt].u[2] = va.z; a[mt].u[3] = va.w;
            }
            #pragma unroll
            for (int nt = 0; nt < 4; nt++) {
                int row = wc + nt * 16 + l15;
                uint4 vb = *(const uint4*)&Bp[row * 64 + ((s ^ (row & 7)) << 3)];
                b[nt].u[0] = vb.x; b[nt].u[1] = vb.y; b[nt].u[2] = vb.z; b[nt].u[3] = vb.w;
            }
            #pragma unroll
            for (int nt = 0; nt < 4; nt++)
                #pragma unroll
                for (int mt = 0; mt < 4; mt++)
                    acc[mt][nt] = __builtin_amdgcn_mfma_f32_16x16x32_bf16(a[mt].v, b[nt].v, acc[mt][nt], 0, 0, 0);
        }
        if (kt + 1 < NKT) {
            SWRITE(cur ^ 1);    // other buffer: safe vs concurrent readers of `cur`
            __syncthreads();    // new tile visible for next iteration
        }
    }

    // epilogue: C/D layout col=lane&15, row=(lane>>4)*4+i  (direct stores)
    #pragma unroll
    for (int nt = 0; nt < 4; nt++) {
        int col = n0 + wc + nt * 16 + l15;
        float bvv = (MODE >= 1) ? bias[col] : 0.f;
        #pragma unroll
        for (int mt = 0; mt < 4; mt++) {
            #pragma unroll
            for (int i = 0; i < 4; i++) {
                int row = m0 + wr + mt * 16 + kg * 4 + i;
                if (row < M) {
                    float v = acc[mt][nt][i] + bvv;
                    if (MODE == 0) {
                        ((unsigned char*)Cv)[(size_t)row * NCOL + col] = f2fp8(v);
                    } else {
                        if (MODE == 2) {
                            v += bf2f(haccp[(size_t)row * DL + col]);
                            v = sigmoidf_(v);
                        }
                        ((ushort*)Cv)[(size_t)row * NCOL + col] = f2bf(v);
                    }
                }
            }
        }
    }
}

// ---------------- flat CSR gather-accumulate over relations [relStart, relEnd) ----
// hrc is fp8 (halved gather bytes); hacc bf16. Half-wave per node, 8 cols
// (8B fp8) per lane; edges in 4-wide batches (clamped idx + zero weight).
__global__ __launch_bounds__(256) void gather_acc(
    const unsigned char* __restrict__ hrc,  // [N][chc] fp8
    const int* __restrict__ eidx,
    const float* __restrict__ ew,
    const int* __restrict__ offs,    // [N*8]
    ushort* __restrict__ hacc,       // [N][256] bf16
    int relStart, int relEnd, int first)
{
    int t = threadIdx.x;
    int slot = t >> 5;               // 0..7
    int l = t & 31;
    int n = blockIdx.x * 8 + slot;
    if (n >= NN) return;
    int e    = offs[n * 8 + relStart];
    int endE = (relEnd == 8 && n == NN - 1) ? EE : offs[n * 8 + relEnd];
    int c = l * 8;

    float acc[8];
    if (first) {
        #pragma unroll
        for (int q = 0; q < 8; q++) acc[q] = 0.f;
    } else {
        uint4 a = *(const uint4*)&hacc[(size_t)n * DL + c];
        unp8(acc, a);
    }

    for (; e < endE; e += 4) {
        int e1 = min(e + 1, endE - 1);
        int e2 = min(e + 2, endE - 1);
        int e3 = min(e + 3, endE - 1);
        int i0 = eidx[e], i1 = eidx[e1], i2 = eidx[e2], i3 = eidx[e3];
        float w0 = ew[e];
        float w1 = (e + 1 < endE) ? ew[e1] : 0.f;
        float w2 = (e + 2 < endE) ? ew[e2] : 0.f;
        float w3 = (e + 3 < endE) ? ew[e3] : 0.f;
        uint2 v0 = *(const uint2*)&hrc[(size_t)i0 + c];
        uint2 v1 = *(const uint2*)&hrc[(size_t)i1 + c];
        uint2 v2 = *(const uint2*)&hrc[(size_t)i2 + c];
        uint2 v3 = *(const uint2*)&hrc[(size_t)i3 + c];
        accf8(acc, v0, w0); accf8(acc, v1, w1);
        accf8(acc, v2, w2); accf8(acc, v3, w3);
    }

    *(uint4*)&hacc[(size_t)n * DL + c] = pack8bf(acc);
}

// ---------------- BatchNorm stats over hg1 columns (vectorized) ----------------
__global__ __launch_bounds__(256) void bnstats_kernel(
    const ushort* __restrict__ hg1, float* __restrict__ colsum, float* __restrict__ colsum2)
{
    __shared__ float ss[8][256], ss2[8][256];
    int t = threadIdx.x;
    int g = t >> 5, l = t & 31;
    int c = l * 8;
    constexpr int RPB = (NN + 255) / 256;   // 196
    int row0 = blockIdx.x * RPB;
    int rend = min(row0 + RPB, NN);
    float s[8], s2[8];
    #pragma unroll
    for (int q = 0; q < 8; q++) { s[q] = 0.f; s2[q] = 0.f; }
    for (int r = row0 + g; r < rend; r += 8) {
        uint4 v = *(const uint4*)&hg1[(size_t)r * DL + c];
        float f[8]; unp8(f, v);
        #pragma unroll
        for (int q = 0; q < 8; q++) { s[q] += f[q]; s2[q] += f[q] * f[q]; }
    }
    #pragma unroll
    for (int q = 0; q < 8; q++) { ss[g][c + q] = s[q]; ss2[g][c + q] = s2[q]; }
    __syncthreads();
    float ts = 0.f, ts2 = 0.f;
    #pragma unroll
    for (int gg = 0; gg < 8; gg++) { ts += ss[gg][t]; ts2 += ss2[gg][t]; }
    atomicAdd(&colsum[t], ts);
    atomicAdd(&colsum2[t], ts2);
}

__global__ void bnfinal_kernel(
    const float* __restrict__ colsum, const float* __restrict__ colsum2,
    const float* __restrict__ gamma, float* __restrict__ mu, float* __restrict__ aa)
{
    int c = threadIdx.x;
    if (c < DL) {
        float m = colsum[c] / (float)NN;
        float var = colsum2[c] / (float)NN - m * m;
        mu[c] = m;
        aa[c] = rsqrtf(var + 1e-5f) * gamma[c];
    }
}

// ---------------- gate = relu(BN(hg1)) @ Wg2 + bg2 ; segment max ----------------
__global__ __launch_bounds__(256) void gate_kernel(
    const ushort* __restrict__ hg1, const float* __restrict__ mu,
    const float* __restrict__ aa, const float* __restrict__ beta,
    const float* __restrict__ Wg2, const float* __restrict__ bg2,
    const int* __restrict__ batch,
    float* __restrict__ gate, unsigned* __restrict__ gmaxu)
{
    int lane = threadIdx.x & 63;
    int wid = (blockIdx.x * blockDim.x + threadIdx.x) >> 6;
    int nw = (gridDim.x * blockDim.x) >> 6;
    int per = (NN + nw - 1) / nw;
    int n0 = wid * per;
    if (n0 >= NN) return;
    int n1 = min(n0 + per, NN);
    float bg2v = bg2[0];
    float lmax = -3.4e38f;
    int curb = batch[n0];
    for (int n = n0; n < n1; n++) {
        float s = 0.f;
        #pragma unroll
        for (int c = 0; c < 4; c++) {
            int d = c * 64 + lane;
            float v = bf2f(hg1[(size_t)n * DL + d]);
            float xn = (v - mu[d]) * aa[d] + beta[d];
            xn = fmaxf(xn, 0.f);
            s += xn * Wg2[d];
        }
        #pragma unroll
        for (int o = 32; o > 0; o >>= 1) s += __shfl_down(s, o, 64);
        if (lane == 0) {
            float g = s + bg2v;
            gate[n] = g;
            int b = batch[n];
            if (b != curb) {
                atomicMax(&gmaxu[curb], fenc(lmax));
                lmax = -3.4e38f; curb = b;
            }
            lmax = fmaxf(lmax, g);
        }
    }
    if (lane == 0) atomicMax(&gmaxu[curb], fenc(lmax));
}

// ---------------- exp + per-graph denom (contiguous 4-node runs/thread) ----
__global__ __launch_bounds__(256) void expdenom_kernel(
    const float* __restrict__ gate, const int* __restrict__ batch,
    const unsigned* __restrict__ gmaxu, float* __restrict__ ealpha, float* __restrict__ denom)
{
    int tid = blockIdx.x * 256 + threadIdx.x;
    int i0 = tid * 4;
    if (i0 >= NN) return;
    int i1 = min(i0 + 4, NN);
    int curb = batch[i0];
    float m = fdec(gmaxu[curb]);
    float lsum = 0.f;
    for (int i = i0; i < i1; i++) {
        int b = batch[i];
        if (b != curb) {
            atomicAdd(&denom[curb], lsum);
            lsum = 0.f; curb = b; m = fdec(gmaxu[b]);
        }
        float ex = expf(gate[i] - m);
        ealpha[i] = ex;
        lsum += ex;
    }
    atomicAdd(&denom[curb], lsum);
}

// ---------------- pooled[g] = sum (e/denom) * h2[n] (batch sorted, vectorized) ----
__global__ __launch_bounds__(256) void pool_kernel(
    const ushort* __restrict__ h2, const float* __restrict__ ealpha,
    const float* __restrict__ denom, const int* __restrict__ batch,
    float* __restrict__ pooled)
{
    int t = threadIdx.x;
    int g = t >> 5, l = t & 31;
    int c = l * 8;
    int row0 = blockIdx.x * 128 + g * 16;
    if (row0 >= NN) return;
    int rend = min(row0 + 16, NN);
    float acc[8];
    #pragma unroll
    for (int q = 0; q < 8; q++) acc[q] = 0.f;
    int curg = batch[row0];
    for (int r = row0; r < rend; r++) {
        int gb = batch[r];
        if (gb != curg) {
            float inv = 1.0f / denom[curg];
            #pragma unroll
            for (int q = 0; q < 8; q++) atomicAdd(&pooled[curg * DL + c + q], acc[q] * inv);
            #pragma unroll
            for (int q = 0; q < 8; q++) acc[q] = 0.f;
            curg = gb;
        }
        float w = ealpha[r];
        uint4 v = *(const uint4*)&h2[(size_t)r * DL + c];
        accw8(acc, v, w);
    }
    float inv = 1.0f / denom[curg];
    #pragma unroll
    for (int q = 0; q < 8; q++) atomicAdd(&pooled[curg * DL + c + q], acc[q] * inv);
}

__global__ void head_kernel(
    const float* __restrict__ pooled, const float* __restrict__ Wgl,
    const float* __restrict__ bgl, float* __restrict__ out)
{
    int g = blockIdx.x;
    int lane = threadIdx.x;           // 64
    float s = 0.f;
    #pragma unroll
    for (int c = 0; c < 4; c++) {
        int d = c * 64 + lane;
        s += pooled[g * DL + d] * Wgl[d];
    }
    #pragma unroll
    for (int o = 32; o > 0; o >>= 1) s += __shfl_down(s, o, 64);
    if (lane == 0) out[g] = sigmoidf_(s + bgl[0]);
}

extern "C" void kernel_launch(void* const* d_in, const int* in_sizes, int n_in,
                              void* d_out, int out_size, void* d_ws, size_t ws_size,
                              hipStream_t stream)
{
    const int* x      = (const int*)d_in[0];
    const int* ei     = (const int*)d_in[1];
    const int* etype  = (const int*)d_in[2];
    const int* batch  = (const int*)d_in[3];
    const float* e0   = (const float*)d_in[4];
    const float* e1   = (const float*)d_in[5];
    const float* e2   = (const float*)d_in[6];
    const float* e3   = (const float*)d_in[7];
    const float* e4   = (const float*)d_in[8];
    const float* e5   = (const float*)d_in[9];
    const float* W1   = (const float*)d_in[10];
    const float* root1= (const float*)d_in[11];
    const float* b1   = (const float*)d_in[12];
    const float* W2   = (const float*)d_in[13];
    const float* root2= (const float*)d_in[14];
    const float* b2   = (const float*)d_in[15];
    const float* Wg1  = (const float*)d_in[16];
    const float* bg1  = (const float*)d_in[17];
    const float* gamma= (const float*)d_in[18];
    const float* beta = (const float*)d_in[19];
    const float* Wg2  = (const float*)d_in[20];
    const float* bg2  = (const float*)d_in[21];
    const float* Wgl  = (const float*)d_in[22];
    const float* bgl  = (const float*)d_in[23];
    float* out = (float*)d_out;

    const int* esrc_in = ei;          // edge_index[0]
    const int* edst_in = ei + EE;     // edge_index[1]

    char* ws = (char*)d_ws;
    size_t off = 0;
    auto alloc = [&](size_t b) -> char* {
        char* p = ws + off;
        off += (b + 255) & ~(size_t)255;
        return p;
    };
    ushort* hbuf   = (ushort*)alloc((size_t)NN * D0 * 2);    // 38.4 MB: h0, later h2
    ushort* h1     = (ushort*)alloc((size_t)NN * DL * 2);    // 25.6 MB
    ushort* hacc   = (ushort*)alloc((size_t)NN * DL * 2);    // 25.6 MB bf16
    size_t zstart = off;                                     // ---- zeroed region ----
    int*      counts  = (int*)alloc((size_t)NN * RR * 4);
    float*    colsum  = (float*)alloc(DL * 4);
    float*    colsum2 = (float*)alloc(DL * 4);
    unsigned* gmaxu   = (unsigned*)alloc(GG * 4);
    float*    denom   = (float*)alloc(GG * 4);
    float*    pooled  = (float*)alloc((size_t)GG * DL * 4);
    size_t zbytes = off - zstart;                            // ---- end zeroed ----
    int*   offs    = (int*)alloc((size_t)NN * RR * 4);
    int*   cursors = (int*)alloc((size_t)NN * RR * 4);
    int*   eidx    = (int*)alloc((size_t)EE * 4);
    float* ew      = (float*)alloc((size_t)EE * 4);
    int*   blkSums = (int*)alloc(512);
    int*   blkOff  = (int*)alloc(512);
    float* mu      = (float*)alloc(DL * 4);
    float* aa      = (float*)alloc(DL * 4);
    float* gate    = (float*)alloc((size_t)NN * 4);
    float* ealpha  = (float*)alloc((size_t)NN * 4);
    ushort* WbT1   = (ushort*)alloc((size_t)9 * DL * D0 * 2);  // 1.77 MB
    ushort* WbT2   = (ushort*)alloc((size_t)9 * DL * DL * 2);  // 1.18 MB
    ushort* WbTg   = (ushort*)alloc((size_t)1 * DL * DL * 2);  // 131 KB

    // hrc LAST (fp8, 1 B/elem): prefer all-8-relation chunk (102.4 MB ->
    // single GEMM + single gather per layer); fall back to 4 / 2.
    int npc;
    unsigned char* hrc;
    {
        size_t need8 = ((size_t)NN * 8 * DL + 255) & ~(size_t)255;
        size_t need4 = ((size_t)NN * 4 * DL + 255) & ~(size_t)255;
        size_t need2 = ((size_t)NN * 2 * DL + 255) & ~(size_t)255;
        if (off + need8 <= ws_size)      { npc = 8; hrc = (unsigned char*)alloc((size_t)NN * 8 * DL); }
        else if (off + need4 <= ws_size) { npc = 4; hrc = (unsigned char*)alloc((size_t)NN * 4 * DL); }
        else if (off + need2 <= ws_size) { npc = 2; hrc = (unsigned char*)alloc((size_t)NN * 2 * DL); }
        else return;   // fail loudly (wrong output) rather than corrupt
    }
    const int chc = npc * DL;

    ushort* h0  = hbuf;
    ushort* h2  = hbuf;            // h0 dead after layer1's final GEMM
    ushort* hg1 = (ushort*)hrc;    // hrc dead after layer2's last gather

    hipMemsetAsync(ws + zstart, 0, zbytes, stream);

    embed_kernel<<<(NN * 48 + 255) / 256, 256, 0, stream>>>(x, e0, e1, e2, e3, e4, e5, h0);
    count_kernel<<<(EE + 255) / 256, 256, 0, stream>>>(edst_in, etype, counts);

    // weight bf16 transposes
    {
        int tot1 = 9 * DL * D0;
        cvtT_kernel<<<(tot1 + 255) / 256, 256, 0, stream>>>(W1, root1, WbT1, RR, D0);
        int tot2 = 9 * DL * DL;
        cvtT_kernel<<<(tot2 + 255) / 256, 256, 0, stream>>>(W2, root2, WbT2, RR, DL);
        int totg = 1 * DL * DL;
        cvtT_kernel<<<(totg + 255) / 256, 256, 0, stream>>>(nullptr, Wg1, WbTg, 0, DL);
    }

    const int M = NN * RR;
    const int NB = (M + SCAN_CHUNK - 1) / SCAN_CHUNK;   // 98
    scanA_kernel<<<NB, 256, 0, stream>>>(counts, M, blkSums);
    scanB_kernel<<<1, 64, 0, stream>>>(blkSums, NB, blkOff);
    scanC_kernel<<<NB, 256, 0, stream>>>(counts, M, blkOff, offs, cursors);
    scatter_kernel<<<(EE + 255) / 256, 256, 0, stream>>>(esrc_in, edst_in, etype, counts, cursors,
                                                          eidx, ew, chc, npc - 1);

    const int MT = (NN + 127) / 128;   // 391 M-tiles
    const dim3 GC(npc * 2, MT), G2(2, MT);
    const int ABLK = (NN + 7) / 8;

    // ---- layer 1 (IN=384): 8/npc chunk GEMM+gather, then fused root finalize ----
    for (int c0 = 0; c0 < RR; c0 += npc) {
        dense_gemm<D0, 0><<<GC, 256, 0, stream>>>(h0, WbT1 + (size_t)c0 * DL * D0, nullptr, nullptr, hrc, NN, chc);
        gather_acc<<<ABLK, 256, 0, stream>>>(hrc, eidx, ew, offs, hacc, c0, c0 + npc, c0 == 0);
    }
    dense_gemm<D0, 2><<<G2, 256, 0, stream>>>(h0, WbT1 + (size_t)8 * DL * D0, b1, hacc, h1, NN, DL);

    // ---- layer 2 (IN=256) ----
    for (int c0 = 0; c0 < RR; c0 += npc) {
        dense_gemm<DL, 0><<<GC, 256, 0, stream>>>(h1, WbT2 + (size_t)c0 * DL * DL, nullptr, nullptr, hrc, NN, chc);
        gather_acc<<<ABLK, 256, 0, stream>>>(hrc, eidx, ew, offs, hacc, c0, c0 + npc, c0 == 0);
    }
    dense_gemm<DL, 2><<<G2, 256, 0, stream>>>(h1, WbT2 + (size_t)8 * DL * DL, b2, hacc, h2, NN, DL);

    // ---- gate linear (no act; BN follows) ----
    dense_gemm<DL, 1><<<G2, 256, 0, stream>>>(h2, WbTg, bg1, nullptr, hg1, NN, DL);

    bnstats_kernel<<<256, 256, 0, stream>>>(hg1, colsum, colsum2);
    bnfinal_kernel<<<1, 256, 0, stream>>>(colsum, colsum2, gamma, mu, aa);
    gate_kernel<<<512, 256, 0, stream>>>(hg1, mu, aa, beta, Wg2, bg2, batch, gate, gmaxu);
    expdenom_kernel<<<((NN + 3) / 4 + 255) / 256, 256, 0, stream>>>(gate, batch, gmaxu, ealpha, denom);
    pool_kernel<<<(NN + 127) / 128, 256, 0, stream>>>(h2, ealpha, denom, batch, pooled);
    head_kernel<<<GG, 64, 0, stream>>>(pooled, Wgl, bgl, out);
}

// Round 16
// 742.749 us; speedup vs baseline: 1.2724x; 1.2724x over previous
//
#include <hip/hip_runtime.h>
#include <hip/hip_bf16.h>
#include <cstdint>

#define NN 50000
#define EE 800000
#define RR 8
#define GG 128
#define D0 384
#define DL 256

typedef __attribute__((ext_vector_type(8))) short bf16x8;
typedef __attribute__((ext_vector_type(4))) float f32x4;

__device__ __forceinline__ float sigmoidf_(float x) { return 1.0f / (1.0f + expf(-x)); }

__device__ __forceinline__ ushort f2bf(float f) {
    uint u = __float_as_uint(f);
    u += 0x7fffu + ((u >> 16) & 1u);
    return (ushort)(u >> 16);
}
__device__ __forceinline__ uint pack2bf(float lo, float hi) {
    return (uint)f2bf(lo) | ((uint)f2bf(hi) << 16);
}
__device__ __forceinline__ float bf2f(ushort u) {
    return __uint_as_float((uint)u << 16);
}

// acc[0..7] += w * bf16x8(v)
__device__ __forceinline__ void accw8(float* s, uint4 a, float w) {
    s[0] += w * __uint_as_float(a.x << 16);
    s[1] += w * __uint_as_float(a.x & 0xffff0000u);
    s[2] += w * __uint_as_float(a.y << 16);
    s[3] += w * __uint_as_float(a.y & 0xffff0000u);
    s[4] += w * __uint_as_float(a.z << 16);
    s[5] += w * __uint_as_float(a.z & 0xffff0000u);
    s[6] += w * __uint_as_float(a.w << 16);
    s[7] += w * __uint_as_float(a.w & 0xffff0000u);
}

// unpack 8 bf16 to fp32
__device__ __forceinline__ void unp8(float* f, uint4 a) {
    f[0] = __uint_as_float(a.x << 16);
    f[1] = __uint_as_float(a.x & 0xffff0000u);
    f[2] = __uint_as_float(a.y << 16);
    f[3] = __uint_as_float(a.y & 0xffff0000u);
    f[4] = __uint_as_float(a.z << 16);
    f[5] = __uint_as_float(a.z & 0xffff0000u);
    f[6] = __uint_as_float(a.w << 16);
    f[7] = __uint_as_float(a.w & 0xffff0000u);
}
__device__ __forceinline__ uint4 pack8bf(const float* f) {
    uint4 p;
    p.x = pack2bf(f[0], f[1]);
    p.y = pack2bf(f[2], f[3]);
    p.z = pack2bf(f[4], f[5]);
    p.w = pack2bf(f[6], f[7]);
    return p;
}

// order-preserving float->uint encoding for atomicMax
__device__ __forceinline__ unsigned fenc(float x) {
    unsigned u = __float_as_uint(x);
    return (u & 0x80000000u) ? ~u : (u | 0x80000000u);
}
__device__ __forceinline__ float fdec(unsigned u) {
    unsigned b = (u & 0x80000000u) ? (u & 0x7fffffffu) : ~u;
    return __uint_as_float(b);
}

// ---------------- embedding concat: h0[n, 0:384] (bf16) ----------------
__global__ __launch_bounds__(256) void embed_kernel(
    const int* __restrict__ x,
    const float* __restrict__ e0, const float* __restrict__ e1,
    const float* __restrict__ e2, const float* __restrict__ e3,
    const float* __restrict__ e4, const float* __restrict__ e5,
    ushort* __restrict__ h0)
{
    int idx = blockIdx.x * 256 + threadIdx.x;   // over NN*48 8-elem chunks
    if (idx >= NN * 48) return;
    int n = idx / 48;
    int q = idx - n * 48;
    int d = q * 8;
    int tbl = d >> 6;
    int w = d & 63;
    int row = x[n * 6 + tbl];
    const float* src;
    switch (tbl) {
        case 0: src = e0; break; case 1: src = e1; break; case 2: src = e2; break;
        case 3: src = e3; break; case 4: src = e4; break; default: src = e5; break;
    }
    float4 f0 = *(const float4*)&src[row * 64 + w];
    float4 f1 = *(const float4*)&src[row * 64 + w + 4];
    uint4 pk;
    pk.x = pack2bf(f0.x, f0.y);
    pk.y = pack2bf(f0.z, f0.w);
    pk.z = pack2bf(f1.x, f1.y);
    pk.w = pack2bf(f1.z, f1.w);
    *(uint4*)&h0[(size_t)n * D0 + d] = pk;
}

// ---------------- weight convert + transpose: WbT[r*256+n][k] = bf16(W[r][k][n]) ----------------
__global__ __launch_bounds__(256) void cvtT_kernel(
    const float* __restrict__ W, const float* __restrict__ root,
    ushort* __restrict__ WbT, int nrel, int IN)
{
    int idx = blockIdx.x * 256 + threadIdx.x;
    int tot = (nrel + 1) * DL * IN;
    if (idx >= tot) return;
    int k = idx % IN;
    int rn = idx / IN;
    int n = rn % DL;
    int r = rn / DL;
    float v = (r < nrel) ? W[((size_t)r * IN + k) * DL + n] : root[(size_t)k * DL + n];
    WbT[idx] = f2bf(v);
}

// ---------------- CSR build ----------------
__global__ __launch_bounds__(256) void count_kernel(
    const int* __restrict__ dst, const int* __restrict__ et, int* __restrict__ counts)
{
    int i = blockIdx.x * 256 + threadIdx.x;
    if (i < EE) atomicAdd(&counts[dst[i] * RR + et[i]], 1);
}

#define SCAN_CHUNK 4096
__global__ __launch_bounds__(256) void scanA_kernel(const int* __restrict__ cnt, int M, int* __restrict__ blkSums)
{
    __shared__ int s[256];
    int b = blockIdx.x, t = threadIdx.x;
    int base = b * SCAN_CHUNK + t * 16;
    int tot = 0;
    #pragma unroll
    for (int i = 0; i < 16; i++) { int idx = base + i; if (idx < M) tot += cnt[idx]; }
    s[t] = tot; __syncthreads();
    for (int off = 128; off > 0; off >>= 1) {
        if (t < off) s[t] += s[t + off];
        __syncthreads();
    }
    if (t == 0) blkSums[b] = s[0];
}

// wave-parallel exclusive scan over NB<=128 block sums (R15, kept)
__global__ void scanB_kernel(const int* __restrict__ blkSums, int NB, int* __restrict__ blkOff)
{
    int l = threadIdx.x;              // 64 lanes
    int a = (l < NB) ? blkSums[l] : 0;
    int b = (64 + l < NB) ? blkSums[64 + l] : 0;
    int ia = a, ib = b;
    for (int o = 1; o < 64; o <<= 1) {
        int t0 = __shfl_up(ia, o, 64);
        if (l >= o) ia += t0;
        int t1 = __shfl_up(ib, o, 64);
        if (l >= o) ib += t1;
    }
    int tot0 = __shfl(ia, 63, 64);
    if (l < NB) blkOff[l] = ia - a;
    if (64 + l < NB) blkOff[64 + l] = tot0 + ib - b;
}

__global__ __launch_bounds__(256) void scanC_kernel(
    const int* __restrict__ cnt, int M, const int* __restrict__ blkOff,
    int* __restrict__ offs, int* __restrict__ curs)
{
    __shared__ int s[256];
    int b = blockIdx.x, t = threadIdx.x;
    int base = b * SCAN_CHUNK + t * 16;
    int loc[16];
    int tot = 0;
    #pragma unroll
    for (int i = 0; i < 16; i++) {
        int idx = base + i;
        int v = (idx < M) ? cnt[idx] : 0;
        loc[i] = tot; tot += v;
    }
    s[t] = tot; __syncthreads();
    for (int off = 1; off < 256; off <<= 1) {
        int v = (t >= off) ? s[t - off] : 0;
        __syncthreads();
        s[t] += v;
        __syncthreads();
    }
    int texc = s[t] - tot;           // exclusive prefix of this thread
    int bb = blkOff[b];
    #pragma unroll
    for (int i = 0; i < 16; i++) {
        int idx = base + i;
        if (idx < M) { int o = bb + texc + loc[i]; offs[idx] = o; curs[idx] = o; }
    }
}

// scatter: per-edge gather index into the npc-relation chunk
// eidx = src*chc + (r & (npc-1))*256 ; weight 1/cnt.
__global__ __launch_bounds__(256) void scatter_kernel(
    const int* __restrict__ src, const int* __restrict__ dst, const int* __restrict__ et,
    const int* __restrict__ cnts, int* __restrict__ cursors,
    int* __restrict__ eidx, float* __restrict__ ew, int chc, int mask)
{
    int i = blockIdx.x * 256 + threadIdx.x;
    if (i < EE) {
        int r = et[i];
        int b = dst[i] * RR + r;
        int pos = atomicAdd(&cursors[b], 1);
        eidx[pos] = src[i] * chc + (r & mask) * DL;
        ew[pos] = 1.0f / (float)cnts[b];
    }
}

// ---------------- dense bf16 MFMA GEMM: frag-packed DOUBLE-buffered LDS (R14) ----
// Tile BM=128 x BN=128 x BK=64, 4 waves, wave = 64x64 (4x4 16x16 frags).
// Frag-packed XOR-swizzled LDS (single ds_read_b128/frag, 0 conflicts), true
// double buffer (64KB), ONE barrier per K-tile, pinned prefetch
// (sched_barrier(0)), T1 bijective XCD remap (FETCH 152->23MB). bf16 output
// (R15's fp8 epilogue was a measured regression: branchy f2fp8 VALU tail +
// 1-byte scalar stores -> 232us vs 70us; reverted). hacc bf16 (R12 win).
// MODE 0: plain; 1: +bias (gate); 2: +hacc(bf16)+bias+sigmoid (finalize).
template<int K, int MODE>
__global__ __launch_bounds__(256) void dense_gemm(
    const ushort* __restrict__ A,    // [M][K] bf16
    const ushort* __restrict__ Bt,   // [NCOL][K] bf16 (rows = C cols)
    const float* __restrict__ bias,  // [NCOL] (MODE>=1)
    const ushort* __restrict__ haccp,// [M][256] bf16 (MODE==2)
    ushort* __restrict__ C,          // [M][NCOL] bf16
    int M, int NCOL)
{
    constexpr int NKT = K / 64;
    __shared__ __attribute__((aligned(16))) ushort Al[2][128 * 64];  // 2x16 KB
    __shared__ __attribute__((aligned(16))) ushort Bl[2][128 * 64];  // 2x16 KB

    // ---- T1: bijective XCD-chunked remap (m204) ----
    const int nwg  = gridDim.x * gridDim.y;
    const int flat = blockIdx.y * gridDim.x + blockIdx.x;
    const int q8 = nwg >> 3, r8 = nwg & 7;
    const int xcd = flat & 7, pos = flat >> 3;
    const int vid = ((xcd < r8) ? xcd * (q8 + 1) : r8 * (q8 + 1) + (xcd - r8) * q8) + pos;
    const int m0  = (vid / gridDim.x) * 128;
    const int n0  = (vid % gridDim.x) * 128;

    const int t    = threadIdx.x;
    const int lane = t & 63;
    const int wv   = t >> 6;
    const int wr   = (wv >> 1) * 64;  // wave row offset
    const int wc   = (wv & 1) * 64;   // wave col offset
    const int l15  = lane & 15;
    const int kg   = lane >> 4;

    // staging decomposition: thread covers rows sr+32i, global elems [sc, sc+8)
    const int sr = t >> 3;
    const int sc = (t & 7) * 8;
    const int g0 = sc,      g1 = sc + 4;
    const int s0 = ((g0 >> 5) << 2) + ((g0 & 15) >> 2), h0_ = (g0 >> 4) & 1;
    const int s1 = ((g1 >> 5) << 2) + ((g1 & 15) >> 2), h1_ = (g1 >> 4) & 1;

    int arow[4], brow[4];
    #pragma unroll
    for (int i = 0; i < 4; i++) {
        int r = sr + i * 32;
        arow[i] = min(m0 + r, M - 1);
        brow[i] = n0 + r;
    }

    uint4 av[4], bv[4];
    auto SLOAD = [&](int kt) {
        const ushort* Ak = A + kt * 64 + sc;
        const ushort* Bk = Bt + kt * 64 + sc;
        #pragma unroll
        for (int i = 0; i < 4; i++) av[i] = *(const uint4*)(Ak + (size_t)arow[i] * K);
        #pragma unroll
        for (int i = 0; i < 4; i++) bv[i] = *(const uint4*)(Bk + (size_t)brow[i] * K);
    };
    auto SWRITE = [&](int buf) {
        #pragma unroll
        for (int i = 0; i < 4; i++) {
            int row = sr + i * 32;
            int rx  = row & 7;
            int o0  = row * 64 + (((s0 ^ rx) << 3) + h0_ * 4);
            int o1  = row * 64 + (((s1 ^ rx) << 3) + h1_ * 4);
            *(uint2*)&Al[buf][o0] = make_uint2(av[i].x, av[i].y);
            *(uint2*)&Al[buf][o1] = make_uint2(av[i].z, av[i].w);
            *(uint2*)&Bl[buf][o0] = make_uint2(bv[i].x, bv[i].y);
            *(uint2*)&Bl[buf][o1] = make_uint2(bv[i].z, bv[i].w);
        }
    };

    f32x4 acc[4][4];
    #pragma unroll
    for (int mt = 0; mt < 4; mt++)
        #pragma unroll
        for (int nt = 0; nt < 4; nt++) acc[mt][nt] = (f32x4){0.f, 0.f, 0.f, 0.f};

    union FR { bf16x8 v; uint u[4]; };

    SLOAD(0);
    SWRITE(0);
    __syncthreads();

    for (int kt = 0; kt < NKT; kt++) {
        const int cur = kt & 1;
        if (kt + 1 < NKT) {
            SLOAD(kt + 1);                       // issue prefetch...
            __builtin_amdgcn_sched_barrier(0);   // ...pinned before the MFMA phase
        }
        const ushort* Ap = Al[cur];
        const ushort* Bp = Bl[cur];
        #pragma unroll
        for (int kb = 0; kb < 2; kb++) {
            const int s = kb * 4 + kg;
            FR a[4], b[4];
            #pragma unroll
            for (int mt = 0; mt < 4; mt++) {
                int row = wr + mt * 16 + l15;
                uint4 va = *(const uint4*)&Ap[row * 64 + ((s ^ (row & 7)) << 3)];
                a[mt].u[0] = va.x; a[mt].u[1] = va.y; a[mt].u[2] = va.z; a[mt].u[3] = va.w;
            }
            #pragma unroll
            for (int nt = 0; nt < 4; nt++) {
                int row = wc + nt * 16 + l15;
                uint4 vb = *(const uint4*)&Bp[row * 64 + ((s ^ (row & 7)) << 3)];
                b[nt].u[0] = vb.x; b[nt].u[1] = vb.y; b[nt].u[2] = vb.z; b[nt].u[3] = vb.w;
            }
            #pragma unroll
            for (int nt = 0; nt < 4; nt++)
                #pragma unroll
                for (int mt = 0; mt < 4; mt++)
                    acc[mt][nt] = __builtin_amdgcn_mfma_f32_16x16x32_bf16(a[mt].v, b[nt].v, acc[mt][nt], 0, 0, 0);
        }
        if (kt + 1 < NKT) {
            SWRITE(cur ^ 1);    // other buffer: safe vs concurrent readers of `cur`
            __syncthreads();    // new tile visible for next iteration
        }
    }

    // epilogue: C/D layout col=lane&15, row=(lane>>4)*4+i  (direct stores)
    #pragma unroll
    for (int nt = 0; nt < 4; nt++) {
        int col = n0 + wc + nt * 16 + l15;
        float bvv = (MODE >= 1) ? bias[col] : 0.f;
        #pragma unroll
        for (int mt = 0; mt < 4; mt++) {
            #pragma unroll
            for (int i = 0; i < 4; i++) {
                int row = m0 + wr + mt * 16 + kg * 4 + i;
                if (row < M) {
                    float v = acc[mt][nt][i] + bvv;
                    if (MODE == 2) {
                        v += bf2f(haccp[(size_t)row * DL + col]);
                        v = sigmoidf_(v);
                    }
                    C[(size_t)row * NCOL + col] = f2bf(v);
                }
            }
        }
    }
}

// ---------------- flat CSR gather-accumulate over relations [relStart, relEnd) ----
// hrc bf16; hacc bf16 (R12's measured win). Half-wave per node, 8 cols
// (16B) per lane; edges in 4-wide batches (clamped idx + zero weight).
__global__ __launch_bounds__(256) void gather_acc(
    const ushort* __restrict__ hrc,  // [N][chc] bf16
    const int* __restrict__ eidx,
    const float* __restrict__ ew,
    const int* __restrict__ offs,    // [N*8]
    ushort* __restrict__ hacc,       // [N][256] bf16
    int relStart, int relEnd, int first)
{
    int t = threadIdx.x;
    int slot = t >> 5;               // 0..7
    int l = t & 31;
    int n = blockIdx.x * 8 + slot;
    if (n >= NN) return;
    int e    = offs[n * 8 + relStart];
    int endE = (relEnd == 8 && n == NN - 1) ? EE : offs[n * 8 + relEnd];
    int c = l * 8;

    float acc[8];
    if (first) {
        #pragma unroll
        for (int q = 0; q < 8; q++) acc[q] = 0.f;
    } else {
        uint4 a = *(const uint4*)&hacc[(size_t)n * DL + c];
        unp8(acc, a);
    }

    for (; e < endE; e += 4) {
        int e1 = min(e + 1, endE - 1);
        int e2 = min(e + 2, endE - 1);
        int e3 = min(e + 3, endE - 1);
        int i0 = eidx[e], i1 = eidx[e1], i2 = eidx[e2], i3 = eidx[e3];
        float w0 = ew[e];
        float w1 = (e + 1 < endE) ? ew[e1] : 0.f;
        float w2 = (e + 2 < endE) ? ew[e2] : 0.f;
        float w3 = (e + 3 < endE) ? ew[e3] : 0.f;
        uint4 v0 = *(const uint4*)&hrc[(size_t)i0 + c];
        uint4 v1 = *(const uint4*)&hrc[(size_t)i1 + c];
        uint4 v2 = *(const uint4*)&hrc[(size_t)i2 + c];
        uint4 v3 = *(const uint4*)&hrc[(size_t)i3 + c];
        accw8(acc, v0, w0); accw8(acc, v1, w1);
        accw8(acc, v2, w2); accw8(acc, v3, w3);
    }

    *(uint4*)&hacc[(size_t)n * DL + c] = pack8bf(acc);
}

// ---------------- BatchNorm stats over hg1 columns (vectorized) ----------------
__global__ __launch_bounds__(256) void bnstats_kernel(
    const ushort* __restrict__ hg1, float* __restrict__ colsum, float* __restrict__ colsum2)
{
    __shared__ float ss[8][256], ss2[8][256];
    int t = threadIdx.x;
    int g = t >> 5, l = t & 31;
    int c = l * 8;
    constexpr int RPB = (NN + 255) / 256;   // 196
    int row0 = blockIdx.x * RPB;
    int rend = min(row0 + RPB, NN);
    float s[8], s2[8];
    #pragma unroll
    for (int q = 0; q < 8; q++) { s[q] = 0.f; s2[q] = 0.f; }
    for (int r = row0 + g; r < rend; r += 8) {
        uint4 v = *(const uint4*)&hg1[(size_t)r * DL + c];
        float f[8]; unp8(f, v);
        #pragma unroll
        for (int q = 0; q < 8; q++) { s[q] += f[q]; s2[q] += f[q] * f[q]; }
    }
    #pragma unroll
    for (int q = 0; q < 8; q++) { ss[g][c + q] = s[q]; ss2[g][c + q] = s2[q]; }
    __syncthreads();
    float ts = 0.f, ts2 = 0.f;
    #pragma unroll
    for (int gg = 0; gg < 8; gg++) { ts += ss[gg][t]; ts2 += ss2[gg][t]; }
    atomicAdd(&colsum[t], ts);
    atomicAdd(&colsum2[t], ts2);
}

__global__ void bnfinal_kernel(
    const float* __restrict__ colsum, const float* __restrict__ colsum2,
    const float* __restrict__ gamma, float* __restrict__ mu, float* __restrict__ aa)
{
    int c = threadIdx.x;
    if (c < DL) {
        float m = colsum[c] / (float)NN;
        float var = colsum2[c] / (float)NN - m * m;
        mu[c] = m;
        aa[c] = rsqrtf(var + 1e-5f) * gamma[c];
    }
}

// ---------------- gate = relu(BN(hg1)) @ Wg2 + bg2 ; segment max ----------------
__global__ __launch_bounds__(256) void gate_kernel(
    const ushort* __restrict__ hg1, const float* __restrict__ mu,
    const float* __restrict__ aa, const float* __restrict__ beta,
    const float* __restrict__ Wg2, const float* __restrict__ bg2,
    const int* __restrict__ batch,
    float* __restrict__ gate, unsigned* __restrict__ gmaxu)
{
    int lane = threadIdx.x & 63;
    int wid = (blockIdx.x * blockDim.x + threadIdx.x) >> 6;
    int nw = (gridDim.x * blockDim.x) >> 6;
    int per = (NN + nw - 1) / nw;
    int n0 = wid * per;
    if (n0 >= NN) return;
    int n1 = min(n0 + per, NN);
    float bg2v = bg2[0];
    float lmax = -3.4e38f;
    int curb = batch[n0];
    for (int n = n0; n < n1; n++) {
        float s = 0.f;
        #pragma unroll
        for (int c = 0; c < 4; c++) {
            int d = c * 64 + lane;
            float v = bf2f(hg1[(size_t)n * DL + d]);
            float xn = (v - mu[d]) * aa[d] + beta[d];
            xn = fmaxf(xn, 0.f);
            s += xn * Wg2[d];
        }
        #pragma unroll
        for (int o = 32; o > 0; o >>= 1) s += __shfl_down(s, o, 64);
        if (lane == 0) {
            float g = s + bg2v;
            gate[n] = g;
            int b = batch[n];
            if (b != curb) {
                atomicMax(&gmaxu[curb], fenc(lmax));
                lmax = -3.4e38f; curb = b;
            }
            lmax = fmaxf(lmax, g);
        }
    }
    if (lane == 0) atomicMax(&gmaxu[curb], fenc(lmax));
}

// ---------------- exp + per-graph denom (contiguous 4-node runs/thread) ----
__global__ __launch_bounds__(256) void expdenom_kernel(
    const float* __restrict__ gate, const int* __restrict__ batch,
    const unsigned* __restrict__ gmaxu, float* __restrict__ ealpha, float* __restrict__ denom)
{
    int tid = blockIdx.x * 256 + threadIdx.x;
    int i0 = tid * 4;
    if (i0 >= NN) return;
    int i1 = min(i0 + 4, NN);
    int curb = batch[i0];
    float m = fdec(gmaxu[curb]);
    float lsum = 0.f;
    for (int i = i0; i < i1; i++) {
        int b = batch[i];
        if (b != curb) {
            atomicAdd(&denom[curb], lsum);
            lsum = 0.f; curb = b; m = fdec(gmaxu[b]);
        }
        float ex = expf(gate[i] - m);
        ealpha[i] = ex;
        lsum += ex;
    }
    atomicAdd(&denom[curb], lsum);
}

// ---------------- pooled[g] = sum (e/denom) * h2[n] (batch sorted, vectorized) ----
__global__ __launch_bounds__(256) void pool_kernel(
    const ushort* __restrict__ h2, const float* __restrict__ ealpha,
    const float* __restrict__ denom, const int* __restrict__ batch,
    float* __restrict__ pooled)
{
    int t = threadIdx.x;
    int g = t >> 5, l = t & 31;
    int c = l * 8;
    int row0 = blockIdx.x * 128 + g * 16;
    if (row0 >= NN) return;
    int rend = min(row0 + 16, NN);
    float acc[8];
    #pragma unroll
    for (int q = 0; q < 8; q++) acc[q] = 0.f;
    int curg = batch[row0];
    for (int r = row0; r < rend; r++) {
        int gb = batch[r];
        if (gb != curg) {
            float inv = 1.0f / denom[curg];
            #pragma unroll
            for (int q = 0; q < 8; q++) atomicAdd(&pooled[curg * DL + c + q], acc[q] * inv);
            #pragma unroll
            for (int q = 0; q < 8; q++) acc[q] = 0.f;
            curg = gb;
        }
        float w = ealpha[r];
        uint4 v = *(const uint4*)&h2[(size_t)r * DL + c];
        accw8(acc, v, w);
    }
    float inv = 1.0f / denom[curg];
    #pragma unroll
    for (int q = 0; q < 8; q++) atomicAdd(&pooled[curg * DL + c + q], acc[q] * inv);
}

__global__ void head_kernel(
    const float* __restrict__ pooled, const float* __restrict__ Wgl,
    const float* __restrict__ bgl, float* __restrict__ out)
{
    int g = blockIdx.x;
    int lane = threadIdx.x;           // 64
    float s = 0.f;
    #pragma unroll
    for (int c = 0; c < 4; c++) {
        int d = c * 64 + lane;
        s += pooled[g * DL + d] * Wgl[d];
    }
    #pragma unroll
    for (int o = 32; o > 0; o >>= 1) s += __shfl_down(s, o, 64);
    if (lane == 0) out[g] = sigmoidf_(s + bgl[0]);
}

extern "C" void kernel_launch(void* const* d_in, const int* in_sizes, int n_in,
                              void* d_out, int out_size, void* d_ws, size_t ws_size,
                              hipStream_t stream)
{
    const int* x      = (const int*)d_in[0];
    const int* ei     = (const int*)d_in[1];
    const int* etype  = (const int*)d_in[2];
    const int* batch  = (const int*)d_in[3];
    const float* e0   = (const float*)d_in[4];
    const float* e1   = (const float*)d_in[5];
    const float* e2   = (const float*)d_in[6];
    const float* e3   = (const float*)d_in[7];
    const float* e4   = (const float*)d_in[8];
    const float* e5   = (const float*)d_in[9];
    const float* W1   = (const float*)d_in[10];
    const float* root1= (const float*)d_in[11];
    const float* b1   = (const float*)d_in[12];
    const float* W2   = (const float*)d_in[13];
    const float* root2= (const float*)d_in[14];
    const float* b2   = (const float*)d_in[15];
    const float* Wg1  = (const float*)d_in[16];
    const float* bg1  = (const float*)d_in[17];
    const float* gamma= (const float*)d_in[18];
    const float* beta = (const float*)d_in[19];
    const float* Wg2  = (const float*)d_in[20];
    const float* bg2  = (const float*)d_in[21];
    const float* Wgl  = (const float*)d_in[22];
    const float* bgl  = (const float*)d_in[23];
    float* out = (float*)d_out;

    const int* esrc_in = ei;          // edge_index[0]
    const int* edst_in = ei + EE;     // edge_index[1]

    char* ws = (char*)d_ws;
    size_t off = 0;
    auto alloc = [&](size_t b) -> char* {
        char* p = ws + off;
        off += (b + 255) & ~(size_t)255;
        return p;
    };
    ushort* hbuf   = (ushort*)alloc((size_t)NN * D0 * 2);    // 38.4 MB: h0, later h2
    ushort* h1     = (ushort*)alloc((size_t)NN * DL * 2);    // 25.6 MB
    ushort* hacc   = (ushort*)alloc((size_t)NN * DL * 2);    // 25.6 MB bf16
    size_t zstart = off;                                     // ---- zeroed region ----
    int*      counts  = (int*)alloc((size_t)NN * RR * 4);
    float*    colsum  = (float*)alloc(DL * 4);
    float*    colsum2 = (float*)alloc(DL * 4);
    unsigned* gmaxu   = (unsigned*)alloc(GG * 4);
    float*    denom   = (float*)alloc(GG * 4);
    float*    pooled  = (float*)alloc((size_t)GG * DL * 4);
    size_t zbytes = off - zstart;                            // ---- end zeroed ----
    int*   offs    = (int*)alloc((size_t)NN * RR * 4);
    int*   cursors = (int*)alloc((size_t)NN * RR * 4);
    int*   eidx    = (int*)alloc((size_t)EE * 4);
    float* ew      = (float*)alloc((size_t)EE * 4);
    int*   blkSums = (int*)alloc(512);
    int*   blkOff  = (int*)alloc(512);
    float* mu      = (float*)alloc(DL * 4);
    float* aa      = (float*)alloc(DL * 4);
    float* gate    = (float*)alloc((size_t)NN * 4);
    float* ealpha  = (float*)alloc((size_t)NN * 4);
    ushort* WbT1   = (ushort*)alloc((size_t)9 * DL * D0 * 2);  // 1.77 MB
    ushort* WbT2   = (ushort*)alloc((size_t)9 * DL * DL * 2);  // 1.18 MB
    ushort* WbTg   = (ushort*)alloc((size_t)1 * DL * DL * 2);  // 131 KB

    // hrc LAST (bf16): pick 4-relation chunks (102.4 MB) if workspace allows, else 2.
    int npc;
    ushort* hrc;
    {
        size_t need4 = ((size_t)NN * 4 * DL * 2 + 255) & ~(size_t)255;
        size_t need2 = ((size_t)NN * 2 * DL * 2 + 255) & ~(size_t)255;
        if (off + need4 <= ws_size)      { npc = 4; hrc = (ushort*)alloc((size_t)NN * 4 * DL * 2); }
        else if (off + need2 <= ws_size) { npc = 2; hrc = (ushort*)alloc((size_t)NN * 2 * DL * 2); }
        else return;   // fail loudly (wrong output) rather than corrupt
    }
    const int chc = npc * DL;

    ushort* h0  = hbuf;
    ushort* h2  = hbuf;   // h0 dead after layer1's final GEMM
    ushort* hg1 = hrc;    // hrc dead after layer2's last gather

    hipMemsetAsync(ws + zstart, 0, zbytes, stream);

    embed_kernel<<<(NN * 48 + 255) / 256, 256, 0, stream>>>(x, e0, e1, e2, e3, e4, e5, h0);
    count_kernel<<<(EE + 255) / 256, 256, 0, stream>>>(edst_in, etype, counts);

    // weight bf16 transposes
    {
        int tot1 = 9 * DL * D0;
        cvtT_kernel<<<(tot1 + 255) / 256, 256, 0, stream>>>(W1, root1, WbT1, RR, D0);
        int tot2 = 9 * DL * DL;
        cvtT_kernel<<<(tot2 + 255) / 256, 256, 0, stream>>>(W2, root2, WbT2, RR, DL);
        int totg = 1 * DL * DL;
        cvtT_kernel<<<(totg + 255) / 256, 256, 0, stream>>>(nullptr, Wg1, WbTg, 0, DL);
    }

    const int M = NN * RR;
    const int NB = (M + SCAN_CHUNK - 1) / SCAN_CHUNK;   // 98
    scanA_kernel<<<NB, 256, 0, stream>>>(counts, M, blkSums);
    scanB_kernel<<<1, 64, 0, stream>>>(blkSums, NB, blkOff);
    scanC_kernel<<<NB, 256, 0, stream>>>(counts, M, blkOff, offs, cursors);
    scatter_kernel<<<(EE + 255) / 256, 256, 0, stream>>>(esrc_in, edst_in, etype, counts, cursors,
                                                          eidx, ew, chc, npc - 1);

    const int MT = (NN + 127) / 128;   // 391 M-tiles
    const dim3 GC(npc * 2, MT), G2(2, MT);
    const int ABLK = (NN + 7) / 8;

    // ---- layer 1 (IN=384): 8/npc chunks, then fused root+aggregate finalize ----
    for (int c0 = 0; c0 < RR; c0 += npc) {
        dense_gemm<D0, 0><<<GC, 256, 0, stream>>>(h0, WbT1 + (size_t)c0 * DL * D0, nullptr, nullptr, hrc, NN, chc);
        gather_acc<<<ABLK, 256, 0, stream>>>(hrc, eidx, ew, offs, hacc, c0, c0 + npc, c0 == 0);
    }
    dense_gemm<D0, 2><<<G2, 256, 0, stream>>>(h0, WbT1 + (size_t)8 * DL * D0, b1, hacc, h1, NN, DL);

    // ---- layer 2 (IN=256) ----
    for (int c0 = 0; c0 < RR; c0 += npc) {
        dense_gemm<DL, 0><<<GC, 256, 0, stream>>>(h1, WbT2 + (size_t)c0 * DL * DL, nullptr, nullptr, hrc, NN, chc);
        gather_acc<<<ABLK, 256, 0, stream>>>(hrc, eidx, ew, offs, hacc, c0, c0 + npc, c0 == 0);
    }
    dense_gemm<DL, 2><<<G2, 256, 0, stream>>>(h1, WbT2 + (size_t)8 * DL * DL, b2, hacc, h2, NN, DL);

    // ---- gate linear (no act; BN follows) ----
    dense_gemm<DL, 1><<<G2, 256, 0, stream>>>(h2, WbTg, bg1, nullptr, hg1, NN, DL);

    bnstats_kernel<<<256, 256, 0, stream>>>(hg1, colsum, colsum2);
    bnfinal_kernel<<<1, 256, 0, stream>>>(colsum, colsum2, gamma, mu, aa);
    gate_kernel<<<512, 256, 0, stream>>>(hg1, mu, aa, beta, Wg2, bg2, batch, gate, gmaxu);
    expdenom_kernel<<<((NN + 3) / 4 + 255) / 256, 256, 0, stream>>>(gate, batch, gmaxu, ealpha, denom);
    pool_kernel<<<(NN + 127) / 128, 256, 0, stream>>>(h2, ealpha, denom, batch, pooled);
    head_kernel<<<GG, 64, 0, stream>>>(pooled, Wgl, bgl, out);
}

// Round 17
// 705.246 us; speedup vs baseline: 1.3400x; 1.0532x over previous
//
#include <hip/hip_runtime.h>
#include <hip/hip_bf16.h>
#include <cstdint>

#define NN 50000
#define EE 800000
#define RR 8
#define GG 128
#define D0 384
#define DL 256
#define NCR 50       // total embedding rows: 33+5+3+4+2+3

typedef __attribute__((ext_vector_type(8))) short bf16x8;
typedef __attribute__((ext_vector_type(4))) float f32x4;

__device__ __forceinline__ float sigmoidf_(float x) { return 1.0f / (1.0f + expf(-x)); }

__device__ __forceinline__ ushort f2bf(float f) {
    uint u = __float_as_uint(f);
    u += 0x7fffu + ((u >> 16) & 1u);
    return (ushort)(u >> 16);
}
__device__ __forceinline__ uint pack2bf(float lo, float hi) {
    return (uint)f2bf(lo) | ((uint)f2bf(hi) << 16);
}
__device__ __forceinline__ float bf2f(ushort u) {
    return __uint_as_float((uint)u << 16);
}

// acc[0..7] += w * bf16x8(v)
__device__ __forceinline__ void accw8(float* s, uint4 a, float w) {
    s[0] += w * __uint_as_float(a.x << 16);
    s[1] += w * __uint_as_float(a.x & 0xffff0000u);
    s[2] += w * __uint_as_float(a.y << 16);
    s[3] += w * __uint_as_float(a.y & 0xffff0000u);
    s[4] += w * __uint_as_float(a.z << 16);
    s[5] += w * __uint_as_float(a.z & 0xffff0000u);
    s[6] += w * __uint_as_float(a.w << 16);
    s[7] += w * __uint_as_float(a.w & 0xffff0000u);
}

// unpack 8 bf16 to fp32
__device__ __forceinline__ void unp8(float* f, uint4 a) {
    f[0] = __uint_as_float(a.x << 16);
    f[1] = __uint_as_float(a.x & 0xffff0000u);
    f[2] = __uint_as_float(a.y << 16);
    f[3] = __uint_as_float(a.y & 0xffff0000u);
    f[4] = __uint_as_float(a.z << 16);
    f[5] = __uint_as_float(a.z & 0xffff0000u);
    f[6] = __uint_as_float(a.w << 16);
    f[7] = __uint_as_float(a.w & 0xffff0000u);
}
__device__ __forceinline__ uint4 pack8bf(const float* f) {
    uint4 p;
    p.x = pack2bf(f[0], f[1]);
    p.y = pack2bf(f[2], f[3]);
    p.z = pack2bf(f[4], f[5]);
    p.w = pack2bf(f[6], f[7]);
    return p;
}

// order-preserving float->uint encoding for atomicMax
__device__ __forceinline__ unsigned fenc(float x) {
    unsigned u = __float_as_uint(x);
    return (u & 0x80000000u) ? ~u : (u | 0x80000000u);
}
__device__ __forceinline__ float fdec(unsigned u) {
    unsigned b = (u & 0x80000000u) ? (u & 0x7fffffffu) : ~u;
    return __uint_as_float(b);
}

// ---------------- layer-1 LUT build: T[cr][r][col] = emb_row(cr) @ W1[r, slice] ----
// cr enumerates the 50 embedding-table rows (cards 33,5,3,4,2,3); r=8 is root1.
__global__ __launch_bounds__(256) void lutbuild_kernel(
    const float* __restrict__ e0, const float* __restrict__ e1,
    const float* __restrict__ e2, const float* __restrict__ e3,
    const float* __restrict__ e4, const float* __restrict__ e5,
    const float* __restrict__ W1, const float* __restrict__ root1,
    ushort* __restrict__ T)          // [50][9][256] bf16
{
    int b = blockIdx.x;              // 0..449
    int cr = b / 9;
    int r  = b - cr * 9;
    int t, c;
    if      (cr < 33) { t = 0; c = cr; }
    else if (cr < 38) { t = 1; c = cr - 33; }
    else if (cr < 41) { t = 2; c = cr - 38; }
    else if (cr < 45) { t = 3; c = cr - 41; }
    else if (cr < 47) { t = 4; c = cr - 45; }
    else              { t = 5; c = cr - 47; }
    const float* emb;
    switch (t) {
        case 0: emb = e0; break; case 1: emb = e1; break; case 2: emb = e2; break;
        case 3: emb = e3; break; case 4: emb = e4; break; default: emb = e5; break;
    }
    const float* er = emb + c * 64;
    int col = threadIdx.x;           // 256
    const float* Wb = (r < 8) ? (W1 + ((size_t)r * D0 + t * 64) * DL + col)
                              : (root1 + (size_t)(t * 64) * DL + col);
    float s = 0.f;
    #pragma unroll 8
    for (int k = 0; k < 64; k++) s += er[k] * Wb[(size_t)k * DL];
    T[(size_t)(cr * 9 + r) * DL + col] = f2bf(s);
}

// ---------------- layer-1 message production via LDS-cached LUT-sum ----------------
// hrc[n][rr*256+col] = sum_t T[x[n,t]][c0+rr][col]  (replaces the K=384 GEMM).
// LDS holds the [50][NPC][256] bf16 slice (102.4 KB @ NPC=4).
template<int NPC>
__global__ __launch_bounds__(256) void lutsum_kernel(
    const ushort* __restrict__ T,    // [50][9][256] bf16
    const int* __restrict__ x,       // [N][6]
    ushort* __restrict__ hrc,        // [N][NPC*256] bf16
    int c0)
{
    __shared__ ushort Ts[NCR * NPC * 256];
    int t = threadIdx.x;
    for (int i = t; i < NCR * NPC * 256; i += 256) {
        int cr  = i / (NPC * 256);
        int rem = i - cr * (NPC * 256);
        int rr  = rem >> 8;
        int col = rem & 255;
        Ts[i] = T[(size_t)(cr * 9 + c0 + rr) * 256 + col];
    }
    __syncthreads();

    constexpr int NPB = 256 / (32 * NPC);   // nodes per block-iteration
    const int slot = t / (32 * NPC);
    const int rr   = (t >> 5) & (NPC - 1);
    const int l    = t & 31;
    const int c    = l * 8;
    constexpr int CHC_ = NPC * 256;

    for (int base = blockIdx.x * NPB; base < NN; base += gridDim.x * NPB) {
        int n = base + slot;
        if (n < NN) {
            const int* xp = x + n * 6;
            const int cumc[6] = {0, 33, 38, 41, 45, 47};
            float acc[8];
            #pragma unroll
            for (int q = 0; q < 8; q++) acc[q] = 0.f;
            #pragma unroll
            for (int tb = 0; tb < 6; tb++) {
                int cr = cumc[tb] + xp[tb];
                uint4 v = *(const uint4*)&Ts[(cr * NPC + rr) * 256 + c];
                accw8(acc, v, 1.0f);
            }
            *(uint4*)&hrc[(size_t)n * CHC_ + rr * 256 + c] = pack8bf(acc);
        }
    }
}

// ---------------- layer-1 finalize: h1 = sigmoid(LUT_root + hacc + b1) ----------------
__global__ __launch_bounds__(256) void lutfin_kernel(
    const ushort* __restrict__ T, const int* __restrict__ x,
    const ushort* __restrict__ hacc, const float* __restrict__ b1,
    ushort* __restrict__ h1)
{
    __shared__ ushort Ts[NCR * 256];  // root slice (r=8), 25.6 KB
    int t = threadIdx.x;
    for (int i = t; i < NCR * 256; i += 256) {
        int cr = i >> 8, col = i & 255;
        Ts[i] = T[(size_t)(cr * 9 + 8) * 256 + col];
    }
    __syncthreads();

    const int slot = t >> 5;          // 8 nodes per block-iteration
    const int l = t & 31;
    const int c = l * 8;

    for (int base = blockIdx.x * 8; base < NN; base += gridDim.x * 8) {
        int n = base + slot;
        if (n < NN) {
            const int* xp = x + n * 6;
            const int cumc[6] = {0, 33, 38, 41, 45, 47};
            float acc[8];
            float4 b0 = *(const float4*)&b1[c];
            float4 bb = *(const float4*)&b1[c + 4];
            acc[0] = b0.x; acc[1] = b0.y; acc[2] = b0.z; acc[3] = b0.w;
            acc[4] = bb.x; acc[5] = bb.y; acc[6] = bb.z; acc[7] = bb.w;
            #pragma unroll
            for (int tb = 0; tb < 6; tb++) {
                int cr = cumc[tb] + xp[tb];
                uint4 v = *(const uint4*)&Ts[cr * 256 + c];
                accw8(acc, v, 1.0f);
            }
            uint4 hv = *(const uint4*)&hacc[(size_t)n * DL + c];
            float hf[8]; unp8(hf, hv);
            #pragma unroll
            for (int q = 0; q < 8; q++) acc[q] = sigmoidf_(acc[q] + hf[q]);
            *(uint4*)&h1[(size_t)n * DL + c] = pack8bf(acc);
        }
    }
}

// ---------------- weight convert + transpose: WbT[r*256+n][k] = bf16(W[r][k][n]) ----------------
__global__ __launch_bounds__(256) void cvtT_kernel(
    const float* __restrict__ W, const float* __restrict__ root,
    ushort* __restrict__ WbT, int nrel, int IN)
{
    int idx = blockIdx.x * 256 + threadIdx.x;
    int tot = (nrel + 1) * DL * IN;
    if (idx >= tot) return;
    int k = idx % IN;
    int rn = idx / IN;
    int n = rn % DL;
    int r = rn / DL;
    float v = (r < nrel) ? W[((size_t)r * IN + k) * DL + n] : root[(size_t)k * DL + n];
    WbT[idx] = f2bf(v);
}

// ---------------- CSR build ----------------
__global__ __launch_bounds__(256) void count_kernel(
    const int* __restrict__ dst, const int* __restrict__ et, int* __restrict__ counts)
{
    int i = blockIdx.x * 256 + threadIdx.x;
    if (i < EE) atomicAdd(&counts[dst[i] * RR + et[i]], 1);
}

#define SCAN_CHUNK 4096
__global__ __launch_bounds__(256) void scanA_kernel(const int* __restrict__ cnt, int M, int* __restrict__ blkSums)
{
    __shared__ int s[256];
    int b = blockIdx.x, t = threadIdx.x;
    int base = b * SCAN_CHUNK + t * 16;
    int tot = 0;
    #pragma unroll
    for (int i = 0; i < 16; i++) { int idx = base + i; if (idx < M) tot += cnt[idx]; }
    s[t] = tot; __syncthreads();
    for (int off = 128; off > 0; off >>= 1) {
        if (t < off) s[t] += s[t + off];
        __syncthreads();
    }
    if (t == 0) blkSums[b] = s[0];
}

// wave-parallel exclusive scan over NB<=128 block sums (R15, kept)
__global__ void scanB_kernel(const int* __restrict__ blkSums, int NB, int* __restrict__ blkOff)
{
    int l = threadIdx.x;              // 64 lanes
    int a = (l < NB) ? blkSums[l] : 0;
    int b = (64 + l < NB) ? blkSums[64 + l] : 0;
    int ia = a, ib = b;
    for (int o = 1; o < 64; o <<= 1) {
        int t0 = __shfl_up(ia, o, 64);
        if (l >= o) ia += t0;
        int t1 = __shfl_up(ib, o, 64);
        if (l >= o) ib += t1;
    }
    int tot0 = __shfl(ia, 63, 64);
    if (l < NB) blkOff[l] = ia - a;
    if (64 + l < NB) blkOff[64 + l] = tot0 + ib - b;
}

__global__ __launch_bounds__(256) void scanC_kernel(
    const int* __restrict__ cnt, int M, const int* __restrict__ blkOff,
    int* __restrict__ offs, int* __restrict__ curs)
{
    __shared__ int s[256];
    int b = blockIdx.x, t = threadIdx.x;
    int base = b * SCAN_CHUNK + t * 16;
    int loc[16];
    int tot = 0;
    #pragma unroll
    for (int i = 0; i < 16; i++) {
        int idx = base + i;
        int v = (idx < M) ? cnt[idx] : 0;
        loc[i] = tot; tot += v;
    }
    s[t] = tot; __syncthreads();
    for (int off = 1; off < 256; off <<= 1) {
        int v = (t >= off) ? s[t - off] : 0;
        __syncthreads();
        s[t] += v;
        __syncthreads();
    }
    int texc = s[t] - tot;           // exclusive prefix of this thread
    int bb = blkOff[b];
    #pragma unroll
    for (int i = 0; i < 16; i++) {
        int idx = base + i;
        if (idx < M) { int o = bb + texc + loc[i]; offs[idx] = o; curs[idx] = o; }
    }
}

// scatter: per-edge gather index into the npc-relation chunk
// eidx = src*chc + (r & (npc-1))*256 ; weight 1/cnt.
__global__ __launch_bounds__(256) void scatter_kernel(
    const int* __restrict__ src, const int* __restrict__ dst, const int* __restrict__ et,
    const int* __restrict__ cnts, int* __restrict__ cursors,
    int* __restrict__ eidx, float* __restrict__ ew, int chc, int mask)
{
    int i = blockIdx.x * 256 + threadIdx.x;
    if (i < EE) {
        int r = et[i];
        int b = dst[i] * RR + r;
        int pos = atomicAdd(&cursors[b], 1);
        eidx[pos] = src[i] * chc + (r & mask) * DL;
        ew[pos] = 1.0f / (float)cnts[b];
    }
}

// ---------------- dense bf16 MFMA GEMM: frag-packed DOUBLE-buffered LDS (R14) ----
// Layer 2 + gate only now (layer 1 is LUT-based). Frag-packed XOR-swizzled
// LDS, true double buffer (64KB), one barrier/K-tile, pinned prefetch,
// T1 bijective XCD remap. MODE 0: plain; 1: +bias; 2: +hacc+bias+sigmoid.
template<int K, int MODE>
__global__ __launch_bounds__(256) void dense_gemm(
    const ushort* __restrict__ A,    // [M][K] bf16
    const ushort* __restrict__ Bt,   // [NCOL][K] bf16 (rows = C cols)
    const float* __restrict__ bias,  // [NCOL] (MODE>=1)
    const ushort* __restrict__ haccp,// [M][256] bf16 (MODE==2)
    ushort* __restrict__ C,          // [M][NCOL] bf16
    int M, int NCOL)
{
    constexpr int NKT = K / 64;
    __shared__ __attribute__((aligned(16))) ushort Al[2][128 * 64];  // 2x16 KB
    __shared__ __attribute__((aligned(16))) ushort Bl[2][128 * 64];  // 2x16 KB

    // ---- T1: bijective XCD-chunked remap (m204) ----
    const int nwg  = gridDim.x * gridDim.y;
    const int flat = blockIdx.y * gridDim.x + blockIdx.x;
    const int q8 = nwg >> 3, r8 = nwg & 7;
    const int xcd = flat & 7, pos = flat >> 3;
    const int vid = ((xcd < r8) ? xcd * (q8 + 1) : r8 * (q8 + 1) + (xcd - r8) * q8) + pos;
    const int m0  = (vid / gridDim.x) * 128;
    const int n0  = (vid % gridDim.x) * 128;

    const int t    = threadIdx.x;
    const int lane = t & 63;
    const int wv   = t >> 6;
    const int wr   = (wv >> 1) * 64;  // wave row offset
    const int wc   = (wv & 1) * 64;   // wave col offset
    const int l15  = lane & 15;
    const int kg   = lane >> 4;

    // staging decomposition: thread covers rows sr+32i, global elems [sc, sc+8)
    const int sr = t >> 3;
    const int sc = (t & 7) * 8;
    const int g0 = sc,      g1 = sc + 4;
    const int s0 = ((g0 >> 5) << 2) + ((g0 & 15) >> 2), h0_ = (g0 >> 4) & 1;
    const int s1 = ((g1 >> 5) << 2) + ((g1 & 15) >> 2), h1_ = (g1 >> 4) & 1;

    int arow[4], brow[4];
    #pragma unroll
    for (int i = 0; i < 4; i++) {
        int r = sr + i * 32;
        arow[i] = min(m0 + r, M - 1);
        brow[i] = n0 + r;
    }

    uint4 av[4], bv[4];
    auto SLOAD = [&](int kt) {
        const ushort* Ak = A + kt * 64 + sc;
        const ushort* Bk = Bt + kt * 64 + sc;
        #pragma unroll
        for (int i = 0; i < 4; i++) av[i] = *(const uint4*)(Ak + (size_t)arow[i] * K);
        #pragma unroll
        for (int i = 0; i < 4; i++) bv[i] = *(const uint4*)(Bk + (size_t)brow[i] * K);
    };
    auto SWRITE = [&](int buf) {
        #pragma unroll
        for (int i = 0; i < 4; i++) {
            int row = sr + i * 32;
            int rx  = row & 7;
            int o0  = row * 64 + (((s0 ^ rx) << 3) + h0_ * 4);
            int o1  = row * 64 + (((s1 ^ rx) << 3) + h1_ * 4);
            *(uint2*)&Al[buf][o0] = make_uint2(av[i].x, av[i].y);
            *(uint2*)&Al[buf][o1] = make_uint2(av[i].z, av[i].w);
            *(uint2*)&Bl[buf][o0] = make_uint2(bv[i].x, bv[i].y);
            *(uint2*)&Bl[buf][o1] = make_uint2(bv[i].z, bv[i].w);
        }
    };

    f32x4 acc[4][4];
    #pragma unroll
    for (int mt = 0; mt < 4; mt++)
        #pragma unroll
        for (int nt = 0; nt < 4; nt++) acc[mt][nt] = (f32x4){0.f, 0.f, 0.f, 0.f};

    union FR { bf16x8 v; uint u[4]; };

    SLOAD(0);
    SWRITE(0);
    __syncthreads();

    for (int kt = 0; kt < NKT; kt++) {
        const int cur = kt & 1;
        if (kt + 1 < NKT) {
            SLOAD(kt + 1);                       // issue prefetch...
            __builtin_amdgcn_sched_barrier(0);   // ...pinned before the MFMA phase
        }
        const ushort* Ap = Al[cur];
        const ushort* Bp = Bl[cur];
        #pragma unroll
        for (int kb = 0; kb < 2; kb++) {
            const int s = kb * 4 + kg;
            FR a[4], b[4];
            #pragma unroll
            for (int mt = 0; mt < 4; mt++) {
                int row = wr + mt * 16 + l15;
                uint4 va = *(const uint4*)&Ap[row * 64 + ((s ^ (row & 7)) << 3)];
                a[mt].u[0] = va.x; a[mt].u[1] = va.y; a[mt].u[2] = va.z; a[mt].u[3] = va.w;
            }
            #pragma unroll
            for (int nt = 0; nt < 4; nt++) {
                int row = wc + nt * 16 + l15;
                uint4 vb = *(const uint4*)&Bp[row * 64 + ((s ^ (row & 7)) << 3)];
                b[nt].u[0] = vb.x; b[nt].u[1] = vb.y; b[nt].u[2] = vb.z; b[nt].u[3] = vb.w;
            }
            #pragma unroll
            for (int nt = 0; nt < 4; nt++)
                #pragma unroll
                for (int mt = 0; mt < 4; mt++)
                    acc[mt][nt] = __builtin_amdgcn_mfma_f32_16x16x32_bf16(a[mt].v, b[nt].v, acc[mt][nt], 0, 0, 0);
        }
        if (kt + 1 < NKT) {
            SWRITE(cur ^ 1);    // other buffer: safe vs concurrent readers of `cur`
            __syncthreads();    // new tile visible for next iteration
        }
    }

    // epilogue: C/D layout col=lane&15, row=(lane>>4)*4+i  (direct stores)
    #pragma unroll
    for (int nt = 0; nt < 4; nt++) {
        int col = n0 + wc + nt * 16 + l15;
        float bvv = (MODE >= 1) ? bias[col] : 0.f;
        #pragma unroll
        for (int mt = 0; mt < 4; mt++) {
            #pragma unroll
            for (int i = 0; i < 4; i++) {
                int row = m0 + wr + mt * 16 + kg * 4 + i;
                if (row < M) {
                    float v = acc[mt][nt][i] + bvv;
                    if (MODE == 2) {
                        v += bf2f(haccp[(size_t)row * DL + col]);
                        v = sigmoidf_(v);
                    }
                    C[(size_t)row * NCOL + col] = f2bf(v);
                }
            }
        }
    }
}

// ---------------- flat CSR gather-accumulate over relations [relStart, relEnd) ----
__global__ __launch_bounds__(256) void gather_acc(
    const ushort* __restrict__ hrc,  // [N][chc] bf16
    const int* __restrict__ eidx,
    const float* __restrict__ ew,
    const int* __restrict__ offs,    // [N*8]
    ushort* __restrict__ hacc,       // [N][256] bf16
    int relStart, int relEnd, int first)
{
    int t = threadIdx.x;
    int slot = t >> 5;               // 0..7
    int l = t & 31;
    int n = blockIdx.x * 8 + slot;
    if (n >= NN) return;
    int e    = offs[n * 8 + relStart];
    int endE = (relEnd == 8 && n == NN - 1) ? EE : offs[n * 8 + relEnd];
    int c = l * 8;

    float acc[8];
    if (first) {
        #pragma unroll
        for (int q = 0; q < 8; q++) acc[q] = 0.f;
    } else {
        uint4 a = *(const uint4*)&hacc[(size_t)n * DL + c];
        unp8(acc, a);
    }

    for (; e < endE; e += 4) {
        int e1 = min(e + 1, endE - 1);
        int e2 = min(e + 2, endE - 1);
        int e3 = min(e + 3, endE - 1);
        int i0 = eidx[e], i1 = eidx[e1], i2 = eidx[e2], i3 = eidx[e3];
        float w0 = ew[e];
        float w1 = (e + 1 < endE) ? ew[e1] : 0.f;
        float w2 = (e + 2 < endE) ? ew[e2] : 0.f;
        float w3 = (e + 3 < endE) ? ew[e3] : 0.f;
        uint4 v0 = *(const uint4*)&hrc[(size_t)i0 + c];
        uint4 v1 = *(const uint4*)&hrc[(size_t)i1 + c];
        uint4 v2 = *(const uint4*)&hrc[(size_t)i2 + c];
        uint4 v3 = *(const uint4*)&hrc[(size_t)i3 + c];
        accw8(acc, v0, w0); accw8(acc, v1, w1);
        accw8(acc, v2, w2); accw8(acc, v3, w3);
    }

    *(uint4*)&hacc[(size_t)n * DL + c] = pack8bf(acc);
}

// ---------------- BatchNorm stats over hg1 columns (vectorized) ----------------
__global__ __launch_bounds__(256) void bnstats_kernel(
    const ushort* __restrict__ hg1, float* __restrict__ colsum, float* __restrict__ colsum2)
{
    __shared__ float ss[8][256], ss2[8][256];
    int t = threadIdx.x;
    int g = t >> 5, l = t & 31;
    int c = l * 8;
    constexpr int RPB = (NN + 255) / 256;   // 196
    int row0 = blockIdx.x * RPB;
    int rend = min(row0 + RPB, NN);
    float s[8], s2[8];
    #pragma unroll
    for (int q = 0; q < 8; q++) { s[q] = 0.f; s2[q] = 0.f; }
    for (int r = row0 + g; r < rend; r += 8) {
        uint4 v = *(const uint4*)&hg1[(size_t)r * DL + c];
        float f[8]; unp8(f, v);
        #pragma unroll
        for (int q = 0; q < 8; q++) { s[q] += f[q]; s2[q] += f[q] * f[q]; }
    }
    #pragma unroll
    for (int q = 0; q < 8; q++) { ss[g][c + q] = s[q]; ss2[g][c + q] = s2[q]; }
    __syncthreads();
    float ts = 0.f, ts2 = 0.f;
    #pragma unroll
    for (int gg = 0; gg < 8; gg++) { ts += ss[gg][t]; ts2 += ss2[gg][t]; }
    atomicAdd(&colsum[t], ts);
    atomicAdd(&colsum2[t], ts2);
}

__global__ void bnfinal_kernel(
    const float* __restrict__ colsum, const float* __restrict__ colsum2,
    const float* __restrict__ gamma, float* __restrict__ mu, float* __restrict__ aa)
{
    int c = threadIdx.x;
    if (c < DL) {
        float m = colsum[c] / (float)NN;
        float var = colsum2[c] / (float)NN - m * m;
        mu[c] = m;
        aa[c] = rsqrtf(var + 1e-5f) * gamma[c];
    }
}

// ---------------- gate = relu(BN(hg1)) @ Wg2 + bg2 ; segment max ----------------
__global__ __launch_bounds__(256) void gate_kernel(
    const ushort* __restrict__ hg1, const float* __restrict__ mu,
    const float* __restrict__ aa, const float* __restrict__ beta,
    const float* __restrict__ Wg2, const float* __restrict__ bg2,
    const int* __restrict__ batch,
    float* __restrict__ gate, unsigned* __restrict__ gmaxu)
{
    int lane = threadIdx.x & 63;
    int wid = (blockIdx.x * blockDim.x + threadIdx.x) >> 6;
    int nw = (gridDim.x * blockDim.x) >> 6;
    int per = (NN + nw - 1) / nw;
    int n0 = wid * per;
    if (n0 >= NN) return;
    int n1 = min(n0 + per, NN);
    float bg2v = bg2[0];
    float lmax = -3.4e38f;
    int curb = batch[n0];
    for (int n = n0; n < n1; n++) {
        float s = 0.f;
        #pragma unroll
        for (int c = 0; c < 4; c++) {
            int d = c * 64 + lane;
            float v = bf2f(hg1[(size_t)n * DL + d]);
            float xn = (v - mu[d]) * aa[d] + beta[d];
            xn = fmaxf(xn, 0.f);
            s += xn * Wg2[d];
        }
        #pragma unroll
        for (int o = 32; o > 0; o >>= 1) s += __shfl_down(s, o, 64);
        if (lane == 0) {
            float g = s + bg2v;
            gate[n] = g;
            int b = batch[n];
            if (b != curb) {
                atomicMax(&gmaxu[curb], fenc(lmax));
                lmax = -3.4e38f; curb = b;
            }
            lmax = fmaxf(lmax, g);
        }
    }
    if (lane == 0) atomicMax(&gmaxu[curb], fenc(lmax));
}

// ---------------- exp + per-graph denom (contiguous 4-node runs/thread) ----
__global__ __launch_bounds__(256) void expdenom_kernel(
    const float* __restrict__ gate, const int* __restrict__ batch,
    const unsigned* __restrict__ gmaxu, float* __restrict__ ealpha, float* __restrict__ denom)
{
    int tid = blockIdx.x * 256 + threadIdx.x;
    int i0 = tid * 4;
    if (i0 >= NN) return;
    int i1 = min(i0 + 4, NN);
    int curb = batch[i0];
    float m = fdec(gmaxu[curb]);
    float lsum = 0.f;
    for (int i = i0; i < i1; i++) {
        int b = batch[i];
        if (b != curb) {
            atomicAdd(&denom[curb], lsum);
            lsum = 0.f; curb = b; m = fdec(gmaxu[b]);
        }
        float ex = expf(gate[i] - m);
        ealpha[i] = ex;
        lsum += ex;
    }
    atomicAdd(&denom[curb], lsum);
}

// ---------------- pooled[g] = sum (e/denom) * h2[n] (batch sorted, vectorized) ----
__global__ __launch_bounds__(256) void pool_kernel(
    const ushort* __restrict__ h2, const float* __restrict__ ealpha,
    const float* __restrict__ denom, const int* __restrict__ batch,
    float* __restrict__ pooled)
{
    int t = threadIdx.x;
    int g = t >> 5, l = t & 31;
    int c = l * 8;
    int row0 = blockIdx.x * 128 + g * 16;
    if (row0 >= NN) return;
    int rend = min(row0 + 16, NN);
    float acc[8];
    #pragma unroll
    for (int q = 0; q < 8; q++) acc[q] = 0.f;
    int curg = batch[row0];
    for (int r = row0; r < rend; r++) {
        int gb = batch[r];
        if (gb != curg) {
            float inv = 1.0f / denom[curg];
            #pragma unroll
            for (int q = 0; q < 8; q++) atomicAdd(&pooled[curg * DL + c + q], acc[q] * inv);
            #pragma unroll
            for (int q = 0; q < 8; q++) acc[q] = 0.f;
            curg = gb;
        }
        float w = ealpha[r];
        uint4 v = *(const uint4*)&h2[(size_t)r * DL + c];
        accw8(acc, v, w);
    }
    float inv = 1.0f / denom[curg];
    #pragma unroll
    for (int q = 0; q < 8; q++) atomicAdd(&pooled[curg * DL + c + q], acc[q] * inv);
}

__global__ void head_kernel(
    const float* __restrict__ pooled, const float* __restrict__ Wgl,
    const float* __restrict__ bgl, float* __restrict__ out)
{
    int g = blockIdx.x;
    int lane = threadIdx.x;           // 64
    float s = 0.f;
    #pragma unroll
    for (int c = 0; c < 4; c++) {
        int d = c * 64 + lane;
        s += pooled[g * DL + d] * Wgl[d];
    }
    #pragma unroll
    for (int o = 32; o > 0; o >>= 1) s += __shfl_down(s, o, 64);
    if (lane == 0) out[g] = sigmoidf_(s + bgl[0]);
}

extern "C" void kernel_launch(void* const* d_in, const int* in_sizes, int n_in,
                              void* d_out, int out_size, void* d_ws, size_t ws_size,
                              hipStream_t stream)
{
    const int* x      = (const int*)d_in[0];
    const int* ei     = (const int*)d_in[1];
    const int* etype  = (const int*)d_in[2];
    const int* batch  = (const int*)d_in[3];
    const float* e0   = (const float*)d_in[4];
    const float* e1   = (const float*)d_in[5];
    const float* e2   = (const float*)d_in[6];
    const float* e3   = (const float*)d_in[7];
    const float* e4   = (const float*)d_in[8];
    const float* e5   = (const float*)d_in[9];
    const float* W1   = (const float*)d_in[10];
    const float* root1= (const float*)d_in[11];
    const float* b1   = (const float*)d_in[12];
    const float* W2   = (const float*)d_in[13];
    const float* root2= (const float*)d_in[14];
    const float* b2   = (const float*)d_in[15];
    const float* Wg1  = (const float*)d_in[16];
    const float* bg1  = (const float*)d_in[17];
    const float* gamma= (const float*)d_in[18];
    const float* beta = (const float*)d_in[19];
    const float* Wg2  = (const float*)d_in[20];
    const float* bg2  = (const float*)d_in[21];
    const float* Wgl  = (const float*)d_in[22];
    const float* bgl  = (const float*)d_in[23];
    float* out = (float*)d_out;

    const int* esrc_in = ei;          // edge_index[0]
    const int* edst_in = ei + EE;     // edge_index[1]

    char* ws = (char*)d_ws;
    size_t off = 0;
    auto alloc = [&](size_t b) -> char* {
        char* p = ws + off;
        off += (b + 255) & ~(size_t)255;
        return p;
    };
    ushort* hbuf   = (ushort*)alloc((size_t)NN * D0 * 2);    // 38.4 MB: h2
    ushort* h1     = (ushort*)alloc((size_t)NN * DL * 2);    // 25.6 MB
    ushort* hacc   = (ushort*)alloc((size_t)NN * DL * 2);    // 25.6 MB bf16
    size_t zstart = off;                                     // ---- zeroed region ----
    int*      counts  = (int*)alloc((size_t)NN * RR * 4);
    float*    colsum  = (float*)alloc(DL * 4);
    float*    colsum2 = (float*)alloc(DL * 4);
    unsigned* gmaxu   = (unsigned*)alloc(GG * 4);
    float*    denom   = (float*)alloc(GG * 4);
    float*    pooled  = (float*)alloc((size_t)GG * DL * 4);
    size_t zbytes = off - zstart;                            // ---- end zeroed ----
    int*   offs    = (int*)alloc((size_t)NN * RR * 4);
    int*   cursors = (int*)alloc((size_t)NN * RR * 4);
    int*   eidx    = (int*)alloc((size_t)EE * 4);
    float* ew      = (float*)alloc((size_t)EE * 4);
    int*   blkSums = (int*)alloc(512);
    int*   blkOff  = (int*)alloc(512);
    float* mu      = (float*)alloc(DL * 4);
    float* aa      = (float*)alloc(DL * 4);
    float* gate    = (float*)alloc((size_t)NN * 4);
    float* ealpha  = (float*)alloc((size_t)NN * 4);
    ushort* Tlut   = (ushort*)alloc((size_t)NCR * 9 * DL * 2); // 230.4 KB LUT
    ushort* WbT2   = (ushort*)alloc((size_t)9 * DL * DL * 2);  // 1.18 MB
    ushort* WbTg   = (ushort*)alloc((size_t)1 * DL * DL * 2);  // 131 KB

    // hrc LAST (bf16): pick 4-relation chunks (102.4 MB) if workspace allows, else 2.
    int npc;
    ushort* hrc;
    {
        size_t need4 = ((size_t)NN * 4 * DL * 2 + 255) & ~(size_t)255;
        size_t need2 = ((size_t)NN * 2 * DL * 2 + 255) & ~(size_t)255;
        if (off + need4 <= ws_size)      { npc = 4; hrc = (ushort*)alloc((size_t)NN * 4 * DL * 2); }
        else if (off + need2 <= ws_size) { npc = 2; hrc = (ushort*)alloc((size_t)NN * 2 * DL * 2); }
        else return;   // fail loudly (wrong output) rather than corrupt
    }
    const int chc = npc * DL;

    ushort* h2  = hbuf;
    ushort* hg1 = hrc;    // hrc dead after layer2's last gather

    hipMemsetAsync(ws + zstart, 0, zbytes, stream);

    // layer-1 LUT + layer-2/gate weight transposes
    lutbuild_kernel<<<NCR * 9, 256, 0, stream>>>(e0, e1, e2, e3, e4, e5, W1, root1, Tlut);
    count_kernel<<<(EE + 255) / 256, 256, 0, stream>>>(edst_in, etype, counts);
    {
        int tot2 = 9 * DL * DL;
        cvtT_kernel<<<(tot2 + 255) / 256, 256, 0, stream>>>(W2, root2, WbT2, RR, DL);
        int totg = 1 * DL * DL;
        cvtT_kernel<<<(totg + 255) / 256, 256, 0, stream>>>(nullptr, Wg1, WbTg, 0, DL);
    }

    const int M = NN * RR;
    const int NB = (M + SCAN_CHUNK - 1) / SCAN_CHUNK;   // 98
    scanA_kernel<<<NB, 256, 0, stream>>>(counts, M, blkSums);
    scanB_kernel<<<1, 64, 0, stream>>>(blkSums, NB, blkOff);
    scanC_kernel<<<NB, 256, 0, stream>>>(counts, M, blkOff, offs, cursors);
    scatter_kernel<<<(EE + 255) / 256, 256, 0, stream>>>(esrc_in, edst_in, etype, counts, cursors,
                                                          eidx, ew, chc, npc - 1);

    const int MT = (NN + 127) / 128;   // 391 M-tiles
    const dim3 GC(npc * 2, MT), G2(2, MT);
    const int ABLK = (NN + 7) / 8;

    // ---- layer 1 via LUT: per chunk, LUT-sum messages then gather ----
    for (int c0 = 0; c0 < RR; c0 += npc) {
        if (npc == 4) lutsum_kernel<4><<<256, 256, 0, stream>>>(Tlut, x, hrc, c0);
        else          lutsum_kernel<2><<<256, 256, 0, stream>>>(Tlut, x, hrc, c0);
        gather_acc<<<ABLK, 256, 0, stream>>>(hrc, eidx, ew, offs, hacc, c0, c0 + npc, c0 == 0);
    }
    lutfin_kernel<<<512, 256, 0, stream>>>(Tlut, x, hacc, b1, h1);

    // ---- layer 2 (IN=256), GEMM-based ----
    for (int c0 = 0; c0 < RR; c0 += npc) {
        dense_gemm<DL, 0><<<GC, 256, 0, stream>>>(h1, WbT2 + (size_t)c0 * DL * DL, nullptr, nullptr, hrc, NN, chc);
        gather_acc<<<ABLK, 256, 0, stream>>>(hrc, eidx, ew, offs, hacc, c0, c0 + npc, c0 == 0);
    }
    dense_gemm<DL, 2><<<G2, 256, 0, stream>>>(h1, WbT2 + (size_t)8 * DL * DL, b2, hacc, h2, NN, DL);

    // ---- gate linear (no act; BN follows) ----
    dense_gemm<DL, 1><<<G2, 256, 0, stream>>>(h2, WbTg, bg1, nullptr, hg1, NN, DL);

    bnstats_kernel<<<256, 256, 0, stream>>>(hg1, colsum, colsum2);
    bnfinal_kernel<<<1, 256, 0, stream>>>(colsum, colsum2, gamma, mu, aa);
    gate_kernel<<<512, 256, 0, stream>>>(hg1, mu, aa, beta, Wg2, bg2, batch, gate, gmaxu);
    expdenom_kernel<<<((NN + 3) / 4 + 255) / 256, 256, 0, stream>>>(gate, batch, gmaxu, ealpha, denom);
    pool_kernel<<<(NN + 127) / 128, 256, 0, stream>>>(h2, ealpha, denom, batch, pooled);
    head_kernel<<<GG, 64, 0, stream>>>(pooled, Wgl, bgl, out);
}

// Round 18
// 661.197 us; speedup vs baseline: 1.4293x; 1.0666x over previous
//
#include <hip/hip_runtime.h>
#include <hip/hip_bf16.h>
#include <cstdint>

#define NN 50000
#define EE 800000
#define RR 8
#define GG 128
#define D0 384
#define DL 256
#define NCR 50       // total embedding rows: 33+5+3+4+2+3

typedef __attribute__((ext_vector_type(8))) short bf16x8;
typedef __attribute__((ext_vector_type(4))) float f32x4;

__device__ __forceinline__ float sigmoidf_(float x) { return 1.0f / (1.0f + expf(-x)); }

__device__ __forceinline__ ushort f2bf(float f) {
    uint u = __float_as_uint(f);
    u += 0x7fffu + ((u >> 16) & 1u);
    return (ushort)(u >> 16);
}
__device__ __forceinline__ uint pack2bf(float lo, float hi) {
    return (uint)f2bf(lo) | ((uint)f2bf(hi) << 16);
}
__device__ __forceinline__ float bf2f(ushort u) {
    return __uint_as_float((uint)u << 16);
}

// acc[0..7] += w * bf16x8(v)
__device__ __forceinline__ void accw8(float* s, uint4 a, float w) {
    s[0] += w * __uint_as_float(a.x << 16);
    s[1] += w * __uint_as_float(a.x & 0xffff0000u);
    s[2] += w * __uint_as_float(a.y << 16);
    s[3] += w * __uint_as_float(a.y & 0xffff0000u);
    s[4] += w * __uint_as_float(a.z << 16);
    s[5] += w * __uint_as_float(a.z & 0xffff0000u);
    s[6] += w * __uint_as_float(a.w << 16);
    s[7] += w * __uint_as_float(a.w & 0xffff0000u);
}

// unpack 8 bf16 to fp32
__device__ __forceinline__ void unp8(float* f, uint4 a) {
    f[0] = __uint_as_float(a.x << 16);
    f[1] = __uint_as_float(a.x & 0xffff0000u);
    f[2] = __uint_as_float(a.y << 16);
    f[3] = __uint_as_float(a.y & 0xffff0000u);
    f[4] = __uint_as_float(a.z << 16);
    f[5] = __uint_as_float(a.z & 0xffff0000u);
    f[6] = __uint_as_float(a.w << 16);
    f[7] = __uint_as_float(a.w & 0xffff0000u);
}
__device__ __forceinline__ uint4 pack8bf(const float* f) {
    uint4 p;
    p.x = pack2bf(f[0], f[1]);
    p.y = pack2bf(f[2], f[3]);
    p.z = pack2bf(f[4], f[5]);
    p.w = pack2bf(f[6], f[7]);
    return p;
}

// order-preserving float->uint encoding for atomicMax
__device__ __forceinline__ unsigned fenc(float x) {
    unsigned u = __float_as_uint(x);
    return (u & 0x80000000u) ? ~u : (u | 0x80000000u);
}
__device__ __forceinline__ float fdec(unsigned u) {
    unsigned b = (u & 0x80000000u) ? (u & 0x7fffffffu) : ~u;
    return __uint_as_float(b);
}

// ---------------- layer-1 LUT build: T[cr][r][col] = emb_row(cr) @ W1[r, slice] ----
__global__ __launch_bounds__(256) void lutbuild_kernel(
    const float* __restrict__ e0, const float* __restrict__ e1,
    const float* __restrict__ e2, const float* __restrict__ e3,
    const float* __restrict__ e4, const float* __restrict__ e5,
    const float* __restrict__ W1, const float* __restrict__ root1,
    ushort* __restrict__ T)          // [50][9][256] bf16
{
    int b = blockIdx.x;              // 0..449
    int cr = b / 9;
    int r  = b - cr * 9;
    int t, c;
    if      (cr < 33) { t = 0; c = cr; }
    else if (cr < 38) { t = 1; c = cr - 33; }
    else if (cr < 41) { t = 2; c = cr - 38; }
    else if (cr < 45) { t = 3; c = cr - 41; }
    else if (cr < 47) { t = 4; c = cr - 45; }
    else              { t = 5; c = cr - 47; }
    const float* emb;
    switch (t) {
        case 0: emb = e0; break; case 1: emb = e1; break; case 2: emb = e2; break;
        case 3: emb = e3; break; case 4: emb = e4; break; default: emb = e5; break;
    }
    const float* er = emb + c * 64;
    int col = threadIdx.x;           // 256
    const float* Wb = (r < 8) ? (W1 + ((size_t)r * D0 + t * 64) * DL + col)
                              : (root1 + (size_t)(t * 64) * DL + col);
    float s = 0.f;
    #pragma unroll 8
    for (int k = 0; k < 64; k++) s += er[k] * Wb[(size_t)k * DL];
    T[(size_t)(cr * 9 + r) * DL + col] = f2bf(s);
}

// ---------------- layer-1 message production via LDS-cached LUT-sum ----------------
// Block covers a 2-relation pair (blockIdx.y): LDS = 50*2*256*2B = 51.2 KB
// -> 3 blocks/CU (R17's 102.4 KB slice capped occupancy at 1 block/CU).
// hrc[n][(2*pair+rr)*256+col] = sum_t T[x[n,t]][c0+2*pair+rr][col].
template<int NPC>
__global__ __launch_bounds__(256) void lutsum_kernel(
    const ushort* __restrict__ T,    // [50][9][256] bf16
    const int* __restrict__ x,       // [N][6]
    ushort* __restrict__ hrc,        // [N][NPC*256] bf16
    int c0)
{
    __shared__ ushort Ts[NCR * 2 * 256];   // 51.2 KB
    const int pair = blockIdx.y;           // 0..NPC/2-1
    int t = threadIdx.x;
    for (int i = t; i < NCR * 2 * 256; i += 256) {
        int cr  = i >> 9;
        int rem = i & 511;
        int rr  = rem >> 8;
        int col = rem & 255;
        Ts[i] = T[(size_t)(cr * 9 + c0 + 2 * pair + rr) * 256 + col];
    }
    __syncthreads();

    const int slot = t >> 6;          // node 0..3 within iteration
    const int rr   = (t >> 5) & 1;
    const int l    = t & 31;
    const int c    = l * 8;
    constexpr int CHC_ = NPC * 256;
    const int colbase = (2 * pair + rr) * 256 + c;

    for (int base = blockIdx.x * 4; base < NN; base += gridDim.x * 4) {
        int n = base + slot;
        if (n < NN) {
            const int* xp = x + n * 6;
            const int cumc[6] = {0, 33, 38, 41, 45, 47};
            float acc[8];
            #pragma unroll
            for (int q = 0; q < 8; q++) acc[q] = 0.f;
            #pragma unroll
            for (int tb = 0; tb < 6; tb++) {
                int cr = cumc[tb] + xp[tb];
                uint4 v = *(const uint4*)&Ts[(cr * 2 + rr) * 256 + c];
                accw8(acc, v, 1.0f);
            }
            *(uint4*)&hrc[(size_t)n * CHC_ + colbase] = pack8bf(acc);
        }
    }
}

// ---------------- layer-1 finalize: h1 = sigmoid(LUT_root + hacc + b1) ----------------
__global__ __launch_bounds__(256) void lutfin_kernel(
    const ushort* __restrict__ T, const int* __restrict__ x,
    const ushort* __restrict__ hacc, const float* __restrict__ b1,
    ushort* __restrict__ h1)
{
    __shared__ ushort Ts[NCR * 256];  // root slice (r=8), 25.6 KB
    int t = threadIdx.x;
    for (int i = t; i < NCR * 256; i += 256) {
        int cr = i >> 8, col = i & 255;
        Ts[i] = T[(size_t)(cr * 9 + 8) * 256 + col];
    }
    __syncthreads();

    const int slot = t >> 5;          // 8 nodes per block-iteration
    const int l = t & 31;
    const int c = l * 8;

    for (int base = blockIdx.x * 8; base < NN; base += gridDim.x * 8) {
        int n = base + slot;
        if (n < NN) {
            const int* xp = x + n * 6;
            const int cumc[6] = {0, 33, 38, 41, 45, 47};
            float acc[8];
            float4 b0 = *(const float4*)&b1[c];
            float4 bb = *(const float4*)&b1[c + 4];
            acc[0] = b0.x; acc[1] = b0.y; acc[2] = b0.z; acc[3] = b0.w;
            acc[4] = bb.x; acc[5] = bb.y; acc[6] = bb.z; acc[7] = bb.w;
            #pragma unroll
            for (int tb = 0; tb < 6; tb++) {
                int cr = cumc[tb] + xp[tb];
                uint4 v = *(const uint4*)&Ts[cr * 256 + c];
                accw8(acc, v, 1.0f);
            }
            uint4 hv = *(const uint4*)&hacc[(size_t)n * DL + c];
            float hf[8]; unp8(hf, hv);
            #pragma unroll
            for (int q = 0; q < 8; q++) acc[q] = sigmoidf_(acc[q] + hf[q]);
            *(uint4*)&h1[(size_t)n * DL + c] = pack8bf(acc);
        }
    }
}

// ---------------- weight convert + transpose: WbT[r*256+n][k] = bf16(W[r][k][n]) ----------------
__global__ __launch_bounds__(256) void cvtT_kernel(
    const float* __restrict__ W, const float* __restrict__ root,
    ushort* __restrict__ WbT, int nrel, int IN)
{
    int idx = blockIdx.x * 256 + threadIdx.x;
    int tot = (nrel + 1) * DL * IN;
    if (idx >= tot) return;
    int k = idx % IN;
    int rn = idx / IN;
    int n = rn % DL;
    int r = rn / DL;
    float v = (r < nrel) ? W[((size_t)r * IN + k) * DL + n] : root[(size_t)k * DL + n];
    WbT[idx] = f2bf(v);
}

// ---------------- CSR build ----------------
__global__ __launch_bounds__(256) void count_kernel(
    const int* __restrict__ dst, const int* __restrict__ et, int* __restrict__ counts)
{
    int i = blockIdx.x * 256 + threadIdx.x;
    if (i < EE) atomicAdd(&counts[dst[i] * RR + et[i]], 1);
}

#define SCAN_CHUNK 4096
__global__ __launch_bounds__(256) void scanA_kernel(const int* __restrict__ cnt, int M, int* __restrict__ blkSums)
{
    __shared__ int s[256];
    int b = blockIdx.x, t = threadIdx.x;
    int base = b * SCAN_CHUNK + t * 16;
    int tot = 0;
    #pragma unroll
    for (int i = 0; i < 16; i++) { int idx = base + i; if (idx < M) tot += cnt[idx]; }
    s[t] = tot; __syncthreads();
    for (int off = 128; off > 0; off >>= 1) {
        if (t < off) s[t] += s[t + off];
        __syncthreads();
    }
    if (t == 0) blkSums[b] = s[0];
}

// wave-parallel exclusive scan over NB<=128 block sums (R15, kept)
__global__ void scanB_kernel(const int* __restrict__ blkSums, int NB, int* __restrict__ blkOff)
{
    int l = threadIdx.x;              // 64 lanes
    int a = (l < NB) ? blkSums[l] : 0;
    int b = (64 + l < NB) ? blkSums[64 + l] : 0;
    int ia = a, ib = b;
    for (int o = 1; o < 64; o <<= 1) {
        int t0 = __shfl_up(ia, o, 64);
        if (l >= o) ia += t0;
        int t1 = __shfl_up(ib, o, 64);
        if (l >= o) ib += t1;
    }
    int tot0 = __shfl(ia, 63, 64);
    if (l < NB) blkOff[l] = ia - a;
    if (64 + l < NB) blkOff[64 + l] = tot0 + ib - b;
}

__global__ __launch_bounds__(256) void scanC_kernel(
    const int* __restrict__ cnt, int M, const int* __restrict__ blkOff,
    int* __restrict__ offs, int* __restrict__ curs)
{
    __shared__ int s[256];
    int b = blockIdx.x, t = threadIdx.x;
    int base = b * SCAN_CHUNK + t * 16;
    int loc[16];
    int tot = 0;
    #pragma unroll
    for (int i = 0; i < 16; i++) {
        int idx = base + i;
        int v = (idx < M) ? cnt[idx] : 0;
        loc[i] = tot; tot += v;
    }
    s[t] = tot; __syncthreads();
    for (int off = 1; off < 256; off <<= 1) {
        int v = (t >= off) ? s[t - off] : 0;
        __syncthreads();
        s[t] += v;
        __syncthreads();
    }
    int texc = s[t] - tot;           // exclusive prefix of this thread
    int bb = blkOff[b];
    #pragma unroll
    for (int i = 0; i < 16; i++) {
        int idx = base + i;
        if (idx < M) { int o = bb + texc + loc[i]; offs[idx] = o; curs[idx] = o; }
    }
}

// scatter: per-edge gather index into the npc-relation chunk
// eidx = src*chc + (r & (npc-1))*256 ; weight 1/cnt.
__global__ __launch_bounds__(256) void scatter_kernel(
    const int* __restrict__ src, const int* __restrict__ dst, const int* __restrict__ et,
    const int* __restrict__ cnts, int* __restrict__ cursors,
    int* __restrict__ eidx, float* __restrict__ ew, int chc, int mask)
{
    int i = blockIdx.x * 256 + threadIdx.x;
    if (i < EE) {
        int r = et[i];
        int b = dst[i] * RR + r;
        int pos = atomicAdd(&cursors[b], 1);
        eidx[pos] = src[i] * chc + (r & mask) * DL;
        ew[pos] = 1.0f / (float)cnts[b];
    }
}

// ---------------- dense bf16 MFMA GEMM: frag-packed DOUBLE-buffered LDS (R14) ----
// Layer 2 + gate only (layer 1 is LUT-based). Frag-packed XOR-swizzled LDS,
// true double buffer (64KB), one barrier/K-tile, pinned prefetch,
// T1 bijective XCD remap. MODE 0: plain; 1: +bias; 2: +hacc+bias+sigmoid.
template<int K, int MODE>
__global__ __launch_bounds__(256) void dense_gemm(
    const ushort* __restrict__ A,    // [M][K] bf16
    const ushort* __restrict__ Bt,   // [NCOL][K] bf16 (rows = C cols)
    const float* __restrict__ bias,  // [NCOL] (MODE>=1)
    const ushort* __restrict__ haccp,// [M][256] bf16 (MODE==2)
    ushort* __restrict__ C,          // [M][NCOL] bf16
    int M, int NCOL)
{
    constexpr int NKT = K / 64;
    __shared__ __attribute__((aligned(16))) ushort Al[2][128 * 64];  // 2x16 KB
    __shared__ __attribute__((aligned(16))) ushort Bl[2][128 * 64];  // 2x16 KB

    // ---- T1: bijective XCD-chunked remap (m204) ----
    const int nwg  = gridDim.x * gridDim.y;
    const int flat = blockIdx.y * gridDim.x + blockIdx.x;
    const int q8 = nwg >> 3, r8 = nwg & 7;
    const int xcd = flat & 7, pos = flat >> 3;
    const int vid = ((xcd < r8) ? xcd * (q8 + 1) : r8 * (q8 + 1) + (xcd - r8) * q8) + pos;
    const int m0  = (vid / gridDim.x) * 128;
    const int n0  = (vid % gridDim.x) * 128;

    const int t    = threadIdx.x;
    const int lane = t & 63;
    const int wv   = t >> 6;
    const int wr   = (wv >> 1) * 64;  // wave row offset
    const int wc   = (wv & 1) * 64;   // wave col offset
    const int l15  = lane & 15;
    const int kg   = lane >> 4;

    // staging decomposition: thread covers rows sr+32i, global elems [sc, sc+8)
    const int sr = t >> 3;
    const int sc = (t & 7) * 8;
    const int g0 = sc,      g1 = sc + 4;
    const int s0 = ((g0 >> 5) << 2) + ((g0 & 15) >> 2), h0_ = (g0 >> 4) & 1;
    const int s1 = ((g1 >> 5) << 2) + ((g1 & 15) >> 2), h1_ = (g1 >> 4) & 1;

    int arow[4], brow[4];
    #pragma unroll
    for (int i = 0; i < 4; i++) {
        int r = sr + i * 32;
        arow[i] = min(m0 + r, M - 1);
        brow[i] = n0 + r;
    }

    uint4 av[4], bv[4];
    auto SLOAD = [&](int kt) {
        const ushort* Ak = A + kt * 64 + sc;
        const ushort* Bk = Bt + kt * 64 + sc;
        #pragma unroll
        for (int i = 0; i < 4; i++) av[i] = *(const uint4*)(Ak + (size_t)arow[i] * K);
        #pragma unroll
        for (int i = 0; i < 4; i++) bv[i] = *(const uint4*)(Bk + (size_t)brow[i] * K);
    };
    auto SWRITE = [&](int buf) {
        #pragma unroll
        for (int i = 0; i < 4; i++) {
            int row = sr + i * 32;
            int rx  = row & 7;
            int o0  = row * 64 + (((s0 ^ rx) << 3) + h0_ * 4);
            int o1  = row * 64 + (((s1 ^ rx) << 3) + h1_ * 4);
            *(uint2*)&Al[buf][o0] = make_uint2(av[i].x, av[i].y);
            *(uint2*)&Al[buf][o1] = make_uint2(av[i].z, av[i].w);
            *(uint2*)&Bl[buf][o0] = make_uint2(bv[i].x, bv[i].y);
            *(uint2*)&Bl[buf][o1] = make_uint2(bv[i].z, bv[i].w);
        }
    };

    f32x4 acc[4][4];
    #pragma unroll
    for (int mt = 0; mt < 4; mt++)
        #pragma unroll
        for (int nt = 0; nt < 4; nt++) acc[mt][nt] = (f32x4){0.f, 0.f, 0.f, 0.f};

    union FR { bf16x8 v; uint u[4]; };

    SLOAD(0);
    SWRITE(0);
    __syncthreads();

    for (int kt = 0; kt < NKT; kt++) {
        const int cur = kt & 1;
        if (kt + 1 < NKT) {
            SLOAD(kt + 1);                       // issue prefetch...
            __builtin_amdgcn_sched_barrier(0);   // ...pinned before the MFMA phase
        }
        const ushort* Ap = Al[cur];
        const ushort* Bp = Bl[cur];
        #pragma unroll
        for (int kb = 0; kb < 2; kb++) {
            const int s = kb * 4 + kg;
            FR a[4], b[4];
            #pragma unroll
            for (int mt = 0; mt < 4; mt++) {
                int row = wr + mt * 16 + l15;
                uint4 va = *(const uint4*)&Ap[row * 64 + ((s ^ (row & 7)) << 3)];
                a[mt].u[0] = va.x; a[mt].u[1] = va.y; a[mt].u[2] = va.z; a[mt].u[3] = va.w;
            }
            #pragma unroll
            for (int nt = 0; nt < 4; nt++) {
                int row = wc + nt * 16 + l15;
                uint4 vb = *(const uint4*)&Bp[row * 64 + ((s ^ (row & 7)) << 3)];
                b[nt].u[0] = vb.x; b[nt].u[1] = vb.y; b[nt].u[2] = vb.z; b[nt].u[3] = vb.w;
            }
            #pragma unroll
            for (int nt = 0; nt < 4; nt++)
                #pragma unroll
                for (int mt = 0; mt < 4; mt++)
                    acc[mt][nt] = __builtin_amdgcn_mfma_f32_16x16x32_bf16(a[mt].v, b[nt].v, acc[mt][nt], 0, 0, 0);
        }
        if (kt + 1 < NKT) {
            SWRITE(cur ^ 1);    // other buffer: safe vs concurrent readers of `cur`
            __syncthreads();    // new tile visible for next iteration
        }
    }

    // epilogue: C/D layout col=lane&15, row=(lane>>4)*4+i  (direct stores)
    #pragma unroll
    for (int nt = 0; nt < 4; nt++) {
        int col = n0 + wc + nt * 16 + l15;
        float bvv = (MODE >= 1) ? bias[col] : 0.f;
        #pragma unroll
        for (int mt = 0; mt < 4; mt++) {
            #pragma unroll
            for (int i = 0; i < 4; i++) {
                int row = m0 + wr + mt * 16 + kg * 4 + i;
                if (row < M) {
                    float v = acc[mt][nt][i] + bvv;
                    if (MODE == 2) {
                        v += bf2f(haccp[(size_t)row * DL + col]);
                        v = sigmoidf_(v);
                    }
                    C[(size_t)row * NCOL + col] = f2bf(v);
                }
            }
        }
    }
}

// ---------------- flat CSR gather-accumulate over relations [relStart, relEnd) ----
__global__ __launch_bounds__(256) void gather_acc(
    const ushort* __restrict__ hrc,  // [N][chc] bf16
    const int* __restrict__ eidx,
    const float* __restrict__ ew,
    const int* __restrict__ offs,    // [N*8]
    ushort* __restrict__ hacc,       // [N][256] bf16
    int relStart, int relEnd, int first)
{
    int t = threadIdx.x;
    int slot = t >> 5;               // 0..7
    int l = t & 31;
    int n = blockIdx.x * 8 + slot;
    if (n >= NN) return;
    int e    = offs[n * 8 + relStart];
    int endE = (relEnd == 8 && n == NN - 1) ? EE : offs[n * 8 + relEnd];
    int c = l * 8;

    float acc[8];
    if (first) {
        #pragma unroll
        for (int q = 0; q < 8; q++) acc[q] = 0.f;
    } else {
        uint4 a = *(const uint4*)&hacc[(size_t)n * DL + c];
        unp8(acc, a);
    }

    for (; e < endE; e += 4) {
        int e1 = min(e + 1, endE - 1);
        int e2 = min(e + 2, endE - 1);
        int e3 = min(e + 3, endE - 1);
        int i0 = eidx[e], i1 = eidx[e1], i2 = eidx[e2], i3 = eidx[e3];
        float w0 = ew[e];
        float w1 = (e + 1 < endE) ? ew[e1] : 0.f;
        float w2 = (e + 2 < endE) ? ew[e2] : 0.f;
        float w3 = (e + 3 < endE) ? ew[e3] : 0.f;
        uint4 v0 = *(const uint4*)&hrc[(size_t)i0 + c];
        uint4 v1 = *(const uint4*)&hrc[(size_t)i1 + c];
        uint4 v2 = *(const uint4*)&hrc[(size_t)i2 + c];
        uint4 v3 = *(const uint4*)&hrc[(size_t)i3 + c];
        accw8(acc, v0, w0); accw8(acc, v1, w1);
        accw8(acc, v2, w2); accw8(acc, v3, w3);
    }

    *(uint4*)&hacc[(size_t)n * DL + c] = pack8bf(acc);
}

// ---------------- BatchNorm stats over hg1 columns (vectorized) ----------------
__global__ __launch_bounds__(256) void bnstats_kernel(
    const ushort* __restrict__ hg1, float* __restrict__ colsum, float* __restrict__ colsum2)
{
    __shared__ float ss[8][256], ss2[8][256];
    int t = threadIdx.x;
    int g = t >> 5, l = t & 31;
    int c = l * 8;
    constexpr int RPB = (NN + 255) / 256;   // 196
    int row0 = blockIdx.x * RPB;
    int rend = min(row0 + RPB, NN);
    float s[8], s2[8];
    #pragma unroll
    for (int q = 0; q < 8; q++) { s[q] = 0.f; s2[q] = 0.f; }
    for (int r = row0 + g; r < rend; r += 8) {
        uint4 v = *(const uint4*)&hg1[(size_t)r * DL + c];
        float f[8]; unp8(f, v);
        #pragma unroll
        for (int q = 0; q < 8; q++) { s[q] += f[q]; s2[q] += f[q] * f[q]; }
    }
    #pragma unroll
    for (int q = 0; q < 8; q++) { ss[g][c + q] = s[q]; ss2[g][c + q] = s2[q]; }
    __syncthreads();
    float ts = 0.f, ts2 = 0.f;
    #pragma unroll
    for (int gg = 0; gg < 8; gg++) { ts += ss[gg][t]; ts2 += ss2[gg][t]; }
    atomicAdd(&colsum[t], ts);
    atomicAdd(&colsum2[t], ts2);
}

__global__ void bnfinal_kernel(
    const float* __restrict__ colsum, const float* __restrict__ colsum2,
    const float* __restrict__ gamma, float* __restrict__ mu, float* __restrict__ aa)
{
    int c = threadIdx.x;
    if (c < DL) {
        float m = colsum[c] / (float)NN;
        float var = colsum2[c] / (float)NN - m * m;
        mu[c] = m;
        aa[c] = rsqrtf(var + 1e-5f) * gamma[c];
    }
}

// ---------------- gate = relu(BN(hg1)) @ Wg2 + bg2 ; segment max ----------------
__global__ __launch_bounds__(256) void gate_kernel(
    const ushort* __restrict__ hg1, const float* __restrict__ mu,
    const float* __restrict__ aa, const float* __restrict__ beta,
    const float* __restrict__ Wg2, const float* __restrict__ bg2,
    const int* __restrict__ batch,
    float* __restrict__ gate, unsigned* __restrict__ gmaxu)
{
    int lane = threadIdx.x & 63;
    int wid = (blockIdx.x * blockDim.x + threadIdx.x) >> 6;
    int nw = (gridDim.x * blockDim.x) >> 6;
    int per = (NN + nw - 1) / nw;
    int n0 = wid * per;
    if (n0 >= NN) return;
    int n1 = min(n0 + per, NN);
    float bg2v = bg2[0];
    float lmax = -3.4e38f;
    int curb = batch[n0];
    for (int n = n0; n < n1; n++) {
        float s = 0.f;
        #pragma unroll
        for (int c = 0; c < 4; c++) {
            int d = c * 64 + lane;
            float v = bf2f(hg1[(size_t)n * DL + d]);
            float xn = (v - mu[d]) * aa[d] + beta[d];
            xn = fmaxf(xn, 0.f);
            s += xn * Wg2[d];
        }
        #pragma unroll
        for (int o = 32; o > 0; o >>= 1) s += __shfl_down(s, o, 64);
        if (lane == 0) {
            float g = s + bg2v;
            gate[n] = g;
            int b = batch[n];
            if (b != curb) {
                atomicMax(&gmaxu[curb], fenc(lmax));
                lmax = -3.4e38f; curb = b;
            }
            lmax = fmaxf(lmax, g);
        }
    }
    if (lane == 0) atomicMax(&gmaxu[curb], fenc(lmax));
}

// ---------------- exp + per-graph denom (contiguous 4-node runs/thread) ----
__global__ __launch_bounds__(256) void expdenom_kernel(
    const float* __restrict__ gate, const int* __restrict__ batch,
    const unsigned* __restrict__ gmaxu, float* __restrict__ ealpha, float* __restrict__ denom)
{
    int tid = blockIdx.x * 256 + threadIdx.x;
    int i0 = tid * 4;
    if (i0 >= NN) return;
    int i1 = min(i0 + 4, NN);
    int curb = batch[i0];
    float m = fdec(gmaxu[curb]);
    float lsum = 0.f;
    for (int i = i0; i < i1; i++) {
        int b = batch[i];
        if (b != curb) {
            atomicAdd(&denom[curb], lsum);
            lsum = 0.f; curb = b; m = fdec(gmaxu[b]);
        }
        float ex = expf(gate[i] - m);
        ealpha[i] = ex;
        lsum += ex;
    }
    atomicAdd(&denom[curb], lsum);
}

// ---------------- pooled[g] = sum (e/denom) * h2[n] (batch sorted, vectorized) ----
__global__ __launch_bounds__(256) void pool_kernel(
    const ushort* __restrict__ h2, const float* __restrict__ ealpha,
    const float* __restrict__ denom, const int* __restrict__ batch,
    float* __restrict__ pooled)
{
    int t = threadIdx.x;
    int g = t >> 5, l = t & 31;
    int c = l * 8;
    int row0 = blockIdx.x * 128 + g * 16;
    if (row0 >= NN) return;
    int rend = min(row0 + 16, NN);
    float acc[8];
    #pragma unroll
    for (int q = 0; q < 8; q++) acc[q] = 0.f;
    int curg = batch[row0];
    for (int r = row0; r < rend; r++) {
        int gb = batch[r];
        if (gb != curg) {
            float inv = 1.0f / denom[curg];
            #pragma unroll
            for (int q = 0; q < 8; q++) atomicAdd(&pooled[curg * DL + c + q], acc[q] * inv);
            #pragma unroll
            for (int q = 0; q < 8; q++) acc[q] = 0.f;
            curg = gb;
        }
        float w = ealpha[r];
        uint4 v = *(const uint4*)&h2[(size_t)r * DL + c];
        accw8(acc, v, w);
    }
    float inv = 1.0f / denom[curg];
    #pragma unroll
    for (int q = 0; q < 8; q++) atomicAdd(&pooled[curg * DL + c + q], acc[q] * inv);
}

__global__ void head_kernel(
    const float* __restrict__ pooled, const float* __restrict__ Wgl,
    const float* __restrict__ bgl, float* __restrict__ out)
{
    int g = blockIdx.x;
    int lane = threadIdx.x;           // 64
    float s = 0.f;
    #pragma unroll
    for (int c = 0; c < 4; c++) {
        int d = c * 64 + lane;
        s += pooled[g * DL + d] * Wgl[d];
    }
    #pragma unroll
    for (int o = 32; o > 0; o >>= 1) s += __shfl_down(s, o, 64);
    if (lane == 0) out[g] = sigmoidf_(s + bgl[0]);
}

extern "C" void kernel_launch(void* const* d_in, const int* in_sizes, int n_in,
                              void* d_out, int out_size, void* d_ws, size_t ws_size,
                              hipStream_t stream)
{
    const int* x      = (const int*)d_in[0];
    const int* ei     = (const int*)d_in[1];
    const int* etype  = (const int*)d_in[2];
    const int* batch  = (const int*)d_in[3];
    const float* e0   = (const float*)d_in[4];
    const float* e1   = (const float*)d_in[5];
    const float* e2   = (const float*)d_in[6];
    const float* e3   = (const float*)d_in[7];
    const float* e4   = (const float*)d_in[8];
    const float* e5   = (const float*)d_in[9];
    const float* W1   = (const float*)d_in[10];
    const float* root1= (const float*)d_in[11];
    const float* b1   = (const float*)d_in[12];
    const float* W2   = (const float*)d_in[13];
    const float* root2= (const float*)d_in[14];
    const float* b2   = (const float*)d_in[15];
    const float* Wg1  = (const float*)d_in[16];
    const float* bg1  = (const float*)d_in[17];
    const float* gamma= (const float*)d_in[18];
    const float* beta = (const float*)d_in[19];
    const float* Wg2  = (const float*)d_in[20];
    const float* bg2  = (const float*)d_in[21];
    const float* Wgl  = (const float*)d_in[22];
    const float* bgl  = (const float*)d_in[23];
    float* out = (float*)d_out;

    const int* esrc_in = ei;          // edge_index[0]
    const int* edst_in = ei + EE;     // edge_index[1]

    char* ws = (char*)d_ws;
    size_t off = 0;
    auto alloc = [&](size_t b) -> char* {
        char* p = ws + off;
        off += (b + 255) & ~(size_t)255;
        return p;
    };
    ushort* hbuf   = (ushort*)alloc((size_t)NN * D0 * 2);    // 38.4 MB: h2
    ushort* h1     = (ushort*)alloc((size_t)NN * DL * 2);    // 25.6 MB
    ushort* hacc   = (ushort*)alloc((size_t)NN * DL * 2);    // 25.6 MB bf16
    size_t zstart = off;                                     // ---- zeroed region ----
    int*      counts  = (int*)alloc((size_t)NN * RR * 4);
    float*    colsum  = (float*)alloc(DL * 4);
    float*    colsum2 = (float*)alloc(DL * 4);
    unsigned* gmaxu   = (unsigned*)alloc(GG * 4);
    float*    denom   = (float*)alloc(GG * 4);
    float*    pooled  = (float*)alloc((size_t)GG * DL * 4);
    size_t zbytes = off - zstart;                            // ---- end zeroed ----
    int*   offs    = (int*)alloc((size_t)NN * RR * 4);
    int*   cursors = (int*)alloc((size_t)NN * RR * 4);
    int*   eidx    = (int*)alloc((size_t)EE * 4);
    float* ew      = (float*)alloc((size_t)EE * 4);
    int*   blkSums = (int*)alloc(512);
    int*   blkOff  = (int*)alloc(512);
    float* mu      = (float*)alloc(DL * 4);
    float* aa      = (float*)alloc(DL * 4);
    float* gate    = (float*)alloc((size_t)NN * 4);
    float* ealpha  = (float*)alloc((size_t)NN * 4);
    ushort* Tlut   = (ushort*)alloc((size_t)NCR * 9 * DL * 2); // 230.4 KB LUT
    ushort* WbT2   = (ushort*)alloc((size_t)9 * DL * DL * 2);  // 1.18 MB
    ushort* WbTg   = (ushort*)alloc((size_t)1 * DL * DL * 2);  // 131 KB

    // hrc LAST (bf16): pick 4-relation chunks (102.4 MB) if workspace allows, else 2.
    int npc;
    ushort* hrc;
    {
        size_t need4 = ((size_t)NN * 4 * DL * 2 + 255) & ~(size_t)255;
        size_t need2 = ((size_t)NN * 2 * DL * 2 + 255) & ~(size_t)255;
        if (off + need4 <= ws_size)      { npc = 4; hrc = (ushort*)alloc((size_t)NN * 4 * DL * 2); }
        else if (off + need2 <= ws_size) { npc = 2; hrc = (ushort*)alloc((size_t)NN * 2 * DL * 2); }
        else return;   // fail loudly (wrong output) rather than corrupt
    }
    const int chc = npc * DL;

    ushort* h2  = hbuf;
    ushort* hg1 = hrc;    // hrc dead after layer2's last gather

    hipMemsetAsync(ws + zstart, 0, zbytes, stream);

    // layer-1 LUT + layer-2/gate weight transposes
    lutbuild_kernel<<<NCR * 9, 256, 0, stream>>>(e0, e1, e2, e3, e4, e5, W1, root1, Tlut);
    count_kernel<<<(EE + 255) / 256, 256, 0, stream>>>(edst_in, etype, counts);
    {
        int tot2 = 9 * DL * DL;
        cvtT_kernel<<<(tot2 + 255) / 256, 256, 0, stream>>>(W2, root2, WbT2, RR, DL);
        int totg = 1 * DL * DL;
        cvtT_kernel<<<(totg + 255) / 256, 256, 0, stream>>>(nullptr, Wg1, WbTg, 0, DL);
    }

    const int M = NN * RR;
    const int NB = (M + SCAN_CHUNK - 1) / SCAN_CHUNK;   // 98
    scanA_kernel<<<NB, 256, 0, stream>>>(counts, M, blkSums);
    scanB_kernel<<<1, 64, 0, stream>>>(blkSums, NB, blkOff);
    scanC_kernel<<<NB, 256, 0, stream>>>(counts, M, blkOff, offs, cursors);
    scatter_kernel<<<(EE + 255) / 256, 256, 0, stream>>>(esrc_in, edst_in, etype, counts, cursors,
                                                          eidx, ew, chc, npc - 1);

    const int MT = (NN + 127) / 128;   // 391 M-tiles
    const dim3 GC(npc * 2, MT), G2(2, MT);
    const int ABLK = (NN + 7) / 8;

    // ---- layer 1 via LUT: per chunk, LUT-sum messages then gather ----
    for (int c0 = 0; c0 < RR; c0 += npc) {
        dim3 LG(512, npc / 2);
        if (npc == 4) lutsum_kernel<4><<<LG, 256, 0, stream>>>(Tlut, x, hrc, c0);
        else          lutsum_kernel<2><<<LG, 256, 0, stream>>>(Tlut, x, hrc, c0);
        gather_acc<<<ABLK, 256, 0, stream>>>(hrc, eidx, ew, offs, hacc, c0, c0 + npc, c0 == 0);
    }
    lutfin_kernel<<<512, 256, 0, stream>>>(Tlut, x, hacc, b1, h1);

    // ---- layer 2 (IN=256), GEMM-based ----
    for (int c0 = 0; c0 < RR; c0 += npc) {
        dense_gemm<DL, 0><<<GC, 256, 0, stream>>>(h1, WbT2 + (size_t)c0 * DL * DL, nullptr, nullptr, hrc, NN, chc);
        gather_acc<<<ABLK, 256, 0, stream>>>(hrc, eidx, ew, offs, hacc, c0, c0 + npc, c0 == 0);
    }
    dense_gemm<DL, 2><<<G2, 256, 0, stream>>>(h1, WbT2 + (size_t)8 * DL * DL, b2, hacc, h2, NN, DL);

    // ---- gate linear (no act; BN follows) ----
    dense_gemm<DL, 1><<<G2, 256, 0, stream>>>(h2, WbTg, bg1, nullptr, hg1, NN, DL);

    bnstats_kernel<<<256, 256, 0, stream>>>(hg1, colsum, colsum2);
    bnfinal_kernel<<<1, 256, 0, stream>>>(colsum, colsum2, gamma, mu, aa);
    gate_kernel<<<512, 256, 0, stream>>>(hg1, mu, aa, beta, Wg2, bg2, batch, gate, gmaxu);
    expdenom_kernel<<<((NN + 3) / 4 + 255) / 256, 256, 0, stream>>>(gate, batch, gmaxu, ealpha, denom);
    pool_kernel<<<(NN + 127) / 128, 256, 0, stream>>>(h2, ealpha, denom, batch, pooled);
    head_kernel<<<GG, 64, 0, stream>>>(pooled, Wgl, bgl, out);
}

// Round 19
// 623.446 us; speedup vs baseline: 1.5158x; 1.0606x over previous
//
#include <hip/hip_runtime.h>
#include <hip/hip_bf16.h>
#include <cstdint>

#define NN 50000
#define EE 800000
#define RR 8
#define GG 128
#define D0 384
#define DL 256
#define NCR 50       // total embedding rows: 33+5+3+4+2+3

typedef __attribute__((ext_vector_type(8))) short bf16x8;
typedef __attribute__((ext_vector_type(4))) float f32x4;

__device__ __forceinline__ float sigmoidf_(float x) { return 1.0f / (1.0f + expf(-x)); }

__device__ __forceinline__ ushort f2bf(float f) {
    uint u = __float_as_uint(f);
    u += 0x7fffu + ((u >> 16) & 1u);
    return (ushort)(u >> 16);
}
__device__ __forceinline__ uint pack2bf(float lo, float hi) {
    return (uint)f2bf(lo) | ((uint)f2bf(hi) << 16);
}
__device__ __forceinline__ float bf2f(ushort u) {
    return __uint_as_float((uint)u << 16);
}

// acc[0..7] += w * bf16x8(v)
__device__ __forceinline__ void accw8(float* s, uint4 a, float w) {
    s[0] += w * __uint_as_float(a.x << 16);
    s[1] += w * __uint_as_float(a.x & 0xffff0000u);
    s[2] += w * __uint_as_float(a.y << 16);
    s[3] += w * __uint_as_float(a.y & 0xffff0000u);
    s[4] += w * __uint_as_float(a.z << 16);
    s[5] += w * __uint_as_float(a.z & 0xffff0000u);
    s[6] += w * __uint_as_float(a.w << 16);
    s[7] += w * __uint_as_float(a.w & 0xffff0000u);
}

// unpack 8 bf16 to fp32
__device__ __forceinline__ void unp8(float* f, uint4 a) {
    f[0] = __uint_as_float(a.x << 16);
    f[1] = __uint_as_float(a.x & 0xffff0000u);
    f[2] = __uint_as_float(a.y << 16);
    f[3] = __uint_as_float(a.y & 0xffff0000u);
    f[4] = __uint_as_float(a.z << 16);
    f[5] = __uint_as_float(a.z & 0xffff0000u);
    f[6] = __uint_as_float(a.w << 16);
    f[7] = __uint_as_float(a.w & 0xffff0000u);
}
__device__ __forceinline__ uint4 pack8bf(const float* f) {
    uint4 p;
    p.x = pack2bf(f[0], f[1]);
    p.y = pack2bf(f[2], f[3]);
    p.z = pack2bf(f[4], f[5]);
    p.w = pack2bf(f[6], f[7]);
    return p;
}

// order-preserving float->uint encoding for atomicMax
__device__ __forceinline__ unsigned fenc(float x) {
    unsigned u = __float_as_uint(x);
    return (u & 0x80000000u) ? ~u : (u | 0x80000000u);
}
__device__ __forceinline__ float fdec(unsigned u) {
    unsigned b = (u & 0x80000000u) ? (u & 0x7fffffffu) : ~u;
    return __uint_as_float(b);
}

// ---------------- layer-1 LUT build: T[cr][r][col] = emb_row(cr) @ W1[r, slice] ----
__global__ __launch_bounds__(256) void lutbuild_kernel(
    const float* __restrict__ e0, const float* __restrict__ e1,
    const float* __restrict__ e2, const float* __restrict__ e3,
    const float* __restrict__ e4, const float* __restrict__ e5,
    const float* __restrict__ W1, const float* __restrict__ root1,
    ushort* __restrict__ T)          // [50][9][256] bf16
{
    int b = blockIdx.x;              // 0..449
    int cr = b / 9;
    int r  = b - cr * 9;
    int t, c;
    if      (cr < 33) { t = 0; c = cr; }
    else if (cr < 38) { t = 1; c = cr - 33; }
    else if (cr < 41) { t = 2; c = cr - 38; }
    else if (cr < 45) { t = 3; c = cr - 41; }
    else if (cr < 47) { t = 4; c = cr - 45; }
    else              { t = 5; c = cr - 47; }
    const float* emb;
    switch (t) {
        case 0: emb = e0; break; case 1: emb = e1; break; case 2: emb = e2; break;
        case 3: emb = e3; break; case 4: emb = e4; break; default: emb = e5; break;
    }
    const float* er = emb + c * 64;
    int col = threadIdx.x;           // 256
    const float* Wb = (r < 8) ? (W1 + ((size_t)r * D0 + t * 64) * DL + col)
                              : (root1 + (size_t)(t * 64) * DL + col);
    float s = 0.f;
    #pragma unroll 8
    for (int k = 0; k < 64; k++) s += er[k] * Wb[(size_t)k * DL];
    T[(size_t)(cr * 9 + r) * DL + col] = f2bf(s);
}

// ---------------- layer-1 message production via LDS-cached LUT-sum ----------------
// ONE relation per block (blockIdx.y): LDS = 50*256*2B = 25.6 KB -> 6 blocks/CU
// (R18's 51.2 KB capped at 3). hrc[n][rr*256+col] = sum_t T[x[n,t]][c0+rr][col].
__global__ __launch_bounds__(256) void lutsum_kernel(
    const ushort* __restrict__ T,    // [50][9][256] bf16
    const int* __restrict__ x,       // [N][6]
    ushort* __restrict__ hrc,        // [N][chc] bf16
    int c0, int chc)
{
    __shared__ ushort Ts[NCR * 256];       // 25.6 KB
    const int rr = blockIdx.y;             // relation within chunk
    int t = threadIdx.x;
    for (int i = t; i < NCR * 256; i += 256) {
        int cr = i >> 8, col = i & 255;
        Ts[i] = T[(size_t)(cr * 9 + c0 + rr) * 256 + col];
    }
    __syncthreads();

    const int slot = t >> 5;          // 8 nodes per block-iteration
    const int l    = t & 31;
    const int c    = l * 8;
    const int colbase = rr * 256 + c;

    for (int base = blockIdx.x * 8; base < NN; base += gridDim.x * 8) {
        int n = base + slot;
        if (n < NN) {
            const int* xp = x + n * 6;
            const int cumc[6] = {0, 33, 38, 41, 45, 47};
            float acc[8];
            #pragma unroll
            for (int q = 0; q < 8; q++) acc[q] = 0.f;
            #pragma unroll
            for (int tb = 0; tb < 6; tb++) {
                int cr = cumc[tb] + xp[tb];
                uint4 v = *(const uint4*)&Ts[cr * 256 + c];
                accw8(acc, v, 1.0f);
            }
            *(uint4*)&hrc[(size_t)n * chc + colbase] = pack8bf(acc);
        }
    }
}

// ---------------- layer-1 finalize: h1 = sigmoid(LUT_root + hacc + b1) ----------------
__global__ __launch_bounds__(256) void lutfin_kernel(
    const ushort* __restrict__ T, const int* __restrict__ x,
    const ushort* __restrict__ hacc, const float* __restrict__ b1,
    ushort* __restrict__ h1)
{
    __shared__ ushort Ts[NCR * 256];  // root slice (r=8), 25.6 KB
    int t = threadIdx.x;
    for (int i = t; i < NCR * 256; i += 256) {
        int cr = i >> 8, col = i & 255;
        Ts[i] = T[(size_t)(cr * 9 + 8) * 256 + col];
    }
    __syncthreads();

    const int slot = t >> 5;          // 8 nodes per block-iteration
    const int l = t & 31;
    const int c = l * 8;

    for (int base = blockIdx.x * 8; base < NN; base += gridDim.x * 8) {
        int n = base + slot;
        if (n < NN) {
            const int* xp = x + n * 6;
            const int cumc[6] = {0, 33, 38, 41, 45, 47};
            float acc[8];
            float4 b0 = *(const float4*)&b1[c];
            float4 bb = *(const float4*)&b1[c + 4];
            acc[0] = b0.x; acc[1] = b0.y; acc[2] = b0.z; acc[3] = b0.w;
            acc[4] = bb.x; acc[5] = bb.y; acc[6] = bb.z; acc[7] = bb.w;
            #pragma unroll
            for (int tb = 0; tb < 6; tb++) {
                int cr = cumc[tb] + xp[tb];
                uint4 v = *(const uint4*)&Ts[cr * 256 + c];
                accw8(acc, v, 1.0f);
            }
            uint4 hv = *(const uint4*)&hacc[(size_t)n * DL + c];
            float hf[8]; unp8(hf, hv);
            #pragma unroll
            for (int q = 0; q < 8; q++) acc[q] = sigmoidf_(acc[q] + hf[q]);
            *(uint4*)&h1[(size_t)n * DL + c] = pack8bf(acc);
        }
    }
}

// ---------------- weight convert + transpose: WbT[r*256+n][k] = bf16(W[r][k][n]) ----------------
__global__ __launch_bounds__(256) void cvtT_kernel(
    const float* __restrict__ W, const float* __restrict__ root,
    ushort* __restrict__ WbT, int nrel, int IN)
{
    int idx = blockIdx.x * 256 + threadIdx.x;
    int tot = (nrel + 1) * DL * IN;
    if (idx >= tot) return;
    int k = idx % IN;
    int rn = idx / IN;
    int n = rn % DL;
    int r = rn / DL;
    float v = (r < nrel) ? W[((size_t)r * IN + k) * DL + n] : root[(size_t)k * DL + n];
    WbT[idx] = f2bf(v);
}

// ---------------- CSR build ----------------
__global__ __launch_bounds__(256) void count_kernel(
    const int* __restrict__ dst, const int* __restrict__ et, int* __restrict__ counts)
{
    int i = blockIdx.x * 256 + threadIdx.x;
    if (i < EE) atomicAdd(&counts[dst[i] * RR + et[i]], 1);
}

#define SCAN_CHUNK 4096
__global__ __launch_bounds__(256) void scanA_kernel(const int* __restrict__ cnt, int M, int* __restrict__ blkSums)
{
    __shared__ int s[256];
    int b = blockIdx.x, t = threadIdx.x;
    int base = b * SCAN_CHUNK + t * 16;
    int tot = 0;
    #pragma unroll
    for (int i = 0; i < 16; i++) { int idx = base + i; if (idx < M) tot += cnt[idx]; }
    s[t] = tot; __syncthreads();
    for (int off = 128; off > 0; off >>= 1) {
        if (t < off) s[t] += s[t + off];
        __syncthreads();
    }
    if (t == 0) blkSums[b] = s[0];
}

// wave-parallel exclusive scan over NB<=128 block sums
__global__ void scanB_kernel(const int* __restrict__ blkSums, int NB, int* __restrict__ blkOff)
{
    int l = threadIdx.x;              // 64 lanes
    int a = (l < NB) ? blkSums[l] : 0;
    int b = (64 + l < NB) ? blkSums[64 + l] : 0;
    int ia = a, ib = b;
    for (int o = 1; o < 64; o <<= 1) {
        int t0 = __shfl_up(ia, o, 64);
        if (l >= o) ia += t0;
        int t1 = __shfl_up(ib, o, 64);
        if (l >= o) ib += t1;
    }
    int tot0 = __shfl(ia, 63, 64);
    if (l < NB) blkOff[l] = ia - a;
    if (64 + l < NB) blkOff[64 + l] = tot0 + ib - b;
}

__global__ __launch_bounds__(256) void scanC_kernel(
    const int* __restrict__ cnt, int M, const int* __restrict__ blkOff,
    int* __restrict__ offs, int* __restrict__ curs)
{
    __shared__ int s[256];
    int b = blockIdx.x, t = threadIdx.x;
    int base = b * SCAN_CHUNK + t * 16;
    int loc[16];
    int tot = 0;
    #pragma unroll
    for (int i = 0; i < 16; i++) {
        int idx = base + i;
        int v = (idx < M) ? cnt[idx] : 0;
        loc[i] = tot; tot += v;
    }
    s[t] = tot; __syncthreads();
    for (int off = 1; off < 256; off <<= 1) {
        int v = (t >= off) ? s[t - off] : 0;
        __syncthreads();
        s[t] += v;
        __syncthreads();
    }
    int texc = s[t] - tot;           // exclusive prefix of this thread
    int bb = blkOff[b];
    #pragma unroll
    for (int i = 0; i < 16; i++) {
        int idx = base + i;
        if (idx < M) { int o = bb + texc + loc[i]; offs[idx] = o; curs[idx] = o; }
    }
}

// scatter: per-edge packed (gather index, weight) as int2 -> ONE 8B scattered
// store per edge (was two 4B stores on two cache lines: 82 MB write traffic).
__global__ __launch_bounds__(256) void scatter_kernel(
    const int* __restrict__ src, const int* __restrict__ dst, const int* __restrict__ et,
    const int* __restrict__ cnts, int* __restrict__ cursors,
    int2* __restrict__ epk, int chc, int mask)
{
    int i = blockIdx.x * 256 + threadIdx.x;
    if (i < EE) {
        int r = et[i];
        int b = dst[i] * RR + r;
        int pos = atomicAdd(&cursors[b], 1);
        int2 p;
        p.x = src[i] * chc + (r & mask) * DL;
        p.y = __float_as_int(1.0f / (float)cnts[b]);
        epk[pos] = p;
    }
}

// ---------------- dense bf16 MFMA GEMM: frag-packed DOUBLE-buffered LDS (R14) ----
// Layer 2 + gate only (layer 1 is LUT-based). Frag-packed XOR-swizzled LDS,
// true double buffer (64KB), one barrier/K-tile, pinned prefetch,
// T1 bijective XCD remap. MODE 0: plain; 1: +bias; 2: +hacc+bias+sigmoid.
template<int K, int MODE>
__global__ __launch_bounds__(256) void dense_gemm(
    const ushort* __restrict__ A,    // [M][K] bf16
    const ushort* __restrict__ Bt,   // [NCOL][K] bf16 (rows = C cols)
    const float* __restrict__ bias,  // [NCOL] (MODE>=1)
    const ushort* __restrict__ haccp,// [M][256] bf16 (MODE==2)
    ushort* __restrict__ C,          // [M][NCOL] bf16
    int M, int NCOL)
{
    constexpr int NKT = K / 64;
    __shared__ __attribute__((aligned(16))) ushort Al[2][128 * 64];  // 2x16 KB
    __shared__ __attribute__((aligned(16))) ushort Bl[2][128 * 64];  // 2x16 KB

    // ---- T1: bijective XCD-chunked remap (m204) ----
    const int nwg  = gridDim.x * gridDim.y;
    const int flat = blockIdx.y * gridDim.x + blockIdx.x;
    const int q8 = nwg >> 3, r8 = nwg & 7;
    const int xcd = flat & 7, pos = flat >> 3;
    const int vid = ((xcd < r8) ? xcd * (q8 + 1) : r8 * (q8 + 1) + (xcd - r8) * q8) + pos;
    const int m0  = (vid / gridDim.x) * 128;
    const int n0  = (vid % gridDim.x) * 128;

    const int t    = threadIdx.x;
    const int lane = t & 63;
    const int wv   = t >> 6;
    const int wr   = (wv >> 1) * 64;  // wave row offset
    const int wc   = (wv & 1) * 64;   // wave col offset
    const int l15  = lane & 15;
    const int kg   = lane >> 4;

    // staging decomposition: thread covers rows sr+32i, global elems [sc, sc+8)
    const int sr = t >> 3;
    const int sc = (t & 7) * 8;
    const int g0 = sc,      g1 = sc + 4;
    const int s0 = ((g0 >> 5) << 2) + ((g0 & 15) >> 2), h0_ = (g0 >> 4) & 1;
    const int s1 = ((g1 >> 5) << 2) + ((g1 & 15) >> 2), h1_ = (g1 >> 4) & 1;

    int arow[4], brow[4];
    #pragma unroll
    for (int i = 0; i < 4; i++) {
        int r = sr + i * 32;
        arow[i] = min(m0 + r, M - 1);
        brow[i] = n0 + r;
    }

    uint4 av[4], bv[4];
    auto SLOAD = [&](int kt) {
        const ushort* Ak = A + kt * 64 + sc;
        const ushort* Bk = Bt + kt * 64 + sc;
        #pragma unroll
        for (int i = 0; i < 4; i++) av[i] = *(const uint4*)(Ak + (size_t)arow[i] * K);
        #pragma unroll
        for (int i = 0; i < 4; i++) bv[i] = *(const uint4*)(Bk + (size_t)brow[i] * K);
    };
    auto SWRITE = [&](int buf) {
        #pragma unroll
        for (int i = 0; i < 4; i++) {
            int row = sr + i * 32;
            int rx  = row & 7;
            int o0  = row * 64 + (((s0 ^ rx) << 3) + h0_ * 4);
            int o1  = row * 64 + (((s1 ^ rx) << 3) + h1_ * 4);
            *(uint2*)&Al[buf][o0] = make_uint2(av[i].x, av[i].y);
            *(uint2*)&Al[buf][o1] = make_uint2(av[i].z, av[i].w);
            *(uint2*)&Bl[buf][o0] = make_uint2(bv[i].x, bv[i].y);
            *(uint2*)&Bl[buf][o1] = make_uint2(bv[i].z, bv[i].w);
        }
    };

    f32x4 acc[4][4];
    #pragma unroll
    for (int mt = 0; mt < 4; mt++)
        #pragma unroll
        for (int nt = 0; nt < 4; nt++) acc[mt][nt] = (f32x4){0.f, 0.f, 0.f, 0.f};

    union FR { bf16x8 v; uint u[4]; };

    SLOAD(0);
    SWRITE(0);
    __syncthreads();

    for (int kt = 0; kt < NKT; kt++) {
        const int cur = kt & 1;
        if (kt + 1 < NKT) {
            SLOAD(kt + 1);                       // issue prefetch...
            __builtin_amdgcn_sched_barrier(0);   // ...pinned before the MFMA phase
        }
        const ushort* Ap = Al[cur];
        const ushort* Bp = Bl[cur];
        #pragma unroll
        for (int kb = 0; kb < 2; kb++) {
            const int s = kb * 4 + kg;
            FR a[4], b[4];
            #pragma unroll
            for (int mt = 0; mt < 4; mt++) {
                int row = wr + mt * 16 + l15;
                uint4 va = *(const uint4*)&Ap[row * 64 + ((s ^ (row & 7)) << 3)];
                a[mt].u[0] = va.x; a[mt].u[1] = va.y; a[mt].u[2] = va.z; a[mt].u[3] = va.w;
            }
            #pragma unroll
            for (int nt = 0; nt < 4; nt++) {
                int row = wc + nt * 16 + l15;
                uint4 vb = *(const uint4*)&Bp[row * 64 + ((s ^ (row & 7)) << 3)];
                b[nt].u[0] = vb.x; b[nt].u[1] = vb.y; b[nt].u[2] = vb.z; b[nt].u[3] = vb.w;
            }
            #pragma unroll
            for (int nt = 0; nt < 4; nt++)
                #pragma unroll
                for (int mt = 0; mt < 4; mt++)
                    acc[mt][nt] = __builtin_amdgcn_mfma_f32_16x16x32_bf16(a[mt].v, b[nt].v, acc[mt][nt], 0, 0, 0);
        }
        if (kt + 1 < NKT) {
            SWRITE(cur ^ 1);    // other buffer: safe vs concurrent readers of `cur`
            __syncthreads();    // new tile visible for next iteration
        }
    }

    // epilogue: C/D layout col=lane&15, row=(lane>>4)*4+i  (direct stores)
    #pragma unroll
    for (int nt = 0; nt < 4; nt++) {
        int col = n0 + wc + nt * 16 + l15;
        float bvv = (MODE >= 1) ? bias[col] : 0.f;
        #pragma unroll
        for (int mt = 0; mt < 4; mt++) {
            #pragma unroll
            for (int i = 0; i < 4; i++) {
                int row = m0 + wr + mt * 16 + kg * 4 + i;
                if (row < M) {
                    float v = acc[mt][nt][i] + bvv;
                    if (MODE == 2) {
                        v += bf2f(haccp[(size_t)row * DL + col]);
                        v = sigmoidf_(v);
                    }
                    C[(size_t)row * NCOL + col] = f2bf(v);
                }
            }
        }
    }
}

// ---------------- flat CSR gather-accumulate over relations [relStart, relEnd) ----
// epk packs (index, weight) per edge. Half-wave per node, 8 cols (16B) per
// lane; edges in 4-wide batches (clamped idx + zero weight).
__global__ __launch_bounds__(256) void gather_acc(
    const ushort* __restrict__ hrc,  // [N][chc] bf16
    const int2* __restrict__ epk,
    const int* __restrict__ offs,    // [N*8]
    ushort* __restrict__ hacc,       // [N][256] bf16
    int relStart, int relEnd, int first)
{
    int t = threadIdx.x;
    int slot = t >> 5;               // 0..7
    int l = t & 31;
    int n = blockIdx.x * 8 + slot;
    if (n >= NN) return;
    int e    = offs[n * 8 + relStart];
    int endE = (relEnd == 8 && n == NN - 1) ? EE : offs[n * 8 + relEnd];
    int c = l * 8;

    float acc[8];
    if (first) {
        #pragma unroll
        for (int q = 0; q < 8; q++) acc[q] = 0.f;
    } else {
        uint4 a = *(const uint4*)&hacc[(size_t)n * DL + c];
        unp8(acc, a);
    }

    for (; e < endE; e += 4) {
        int e1 = min(e + 1, endE - 1);
        int e2 = min(e + 2, endE - 1);
        int e3 = min(e + 3, endE - 1);
        int2 p0 = epk[e], p1 = epk[e1], p2 = epk[e2], p3 = epk[e3];
        float w0 = __int_as_float(p0.y);
        float w1 = (e + 1 < endE) ? __int_as_float(p1.y) : 0.f;
        float w2 = (e + 2 < endE) ? __int_as_float(p2.y) : 0.f;
        float w3 = (e + 3 < endE) ? __int_as_float(p3.y) : 0.f;
        uint4 v0 = *(const uint4*)&hrc[(size_t)p0.x + c];
        uint4 v1 = *(const uint4*)&hrc[(size_t)p1.x + c];
        uint4 v2 = *(const uint4*)&hrc[(size_t)p2.x + c];
        uint4 v3 = *(const uint4*)&hrc[(size_t)p3.x + c];
        accw8(acc, v0, w0); accw8(acc, v1, w1);
        accw8(acc, v2, w2); accw8(acc, v3, w3);
    }

    *(uint4*)&hacc[(size_t)n * DL + c] = pack8bf(acc);
}

// ---------------- BatchNorm stats over hg1 columns (vectorized) ----------------
__global__ __launch_bounds__(256) void bnstats_kernel(
    const ushort* __restrict__ hg1, float* __restrict__ colsum, float* __restrict__ colsum2)
{
    __shared__ float ss[8][256], ss2[8][256];
    int t = threadIdx.x;
    int g = t >> 5, l = t & 31;
    int c = l * 8;
    constexpr int RPB = (NN + 255) / 256;   // 196
    int row0 = blockIdx.x * RPB;
    int rend = min(row0 + RPB, NN);
    float s[8], s2[8];
    #pragma unroll
    for (int q = 0; q < 8; q++) { s[q] = 0.f; s2[q] = 0.f; }
    for (int r = row0 + g; r < rend; r += 8) {
        uint4 v = *(const uint4*)&hg1[(size_t)r * DL + c];
        float f[8]; unp8(f, v);
        #pragma unroll
        for (int q = 0; q < 8; q++) { s[q] += f[q]; s2[q] += f[q] * f[q]; }
    }
    #pragma unroll
    for (int q = 0; q < 8; q++) { ss[g][c + q] = s[q]; ss2[g][c + q] = s2[q]; }
    __syncthreads();
    float ts = 0.f, ts2 = 0.f;
    #pragma unroll
    for (int gg = 0; gg < 8; gg++) { ts += ss[gg][t]; ts2 += ss2[gg][t]; }
    atomicAdd(&colsum[t], ts);
    atomicAdd(&colsum2[t], ts2);
}

__global__ void bnfinal_kernel(
    const float* __restrict__ colsum, const float* __restrict__ colsum2,
    const float* __restrict__ gamma, float* __restrict__ mu, float* __restrict__ aa)
{
    int c = threadIdx.x;
    if (c < DL) {
        float m = colsum[c] / (float)NN;
        float var = colsum2[c] / (float)NN - m * m;
        mu[c] = m;
        aa[c] = rsqrtf(var + 1e-5f) * gamma[c];
    }
}

// ---------------- gate = relu(BN(hg1)) @ Wg2 + bg2 ; segment max ----------------
__global__ __launch_bounds__(256) void gate_kernel(
    const ushort* __restrict__ hg1, const float* __restrict__ mu,
    const float* __restrict__ aa, const float* __restrict__ beta,
    const float* __restrict__ Wg2, const float* __restrict__ bg2,
    const int* __restrict__ batch,
    float* __restrict__ gate, unsigned* __restrict__ gmaxu)
{
    int lane = threadIdx.x & 63;
    int wid = (blockIdx.x * blockDim.x + threadIdx.x) >> 6;
    int nw = (gridDim.x * blockDim.x) >> 6;
    int per = (NN + nw - 1) / nw;
    int n0 = wid * per;
    if (n0 >= NN) return;
    int n1 = min(n0 + per, NN);
    float bg2v = bg2[0];
    float lmax = -3.4e38f;
    int curb = batch[n0];
    for (int n = n0; n < n1; n++) {
        float s = 0.f;
        #pragma unroll
        for (int c = 0; c < 4; c++) {
            int d = c * 64 + lane;
            float v = bf2f(hg1[(size_t)n * DL + d]);
            float xn = (v - mu[d]) * aa[d] + beta[d];
            xn = fmaxf(xn, 0.f);
            s += xn * Wg2[d];
        }
        #pragma unroll
        for (int o = 32; o > 0; o >>= 1) s += __shfl_down(s, o, 64);
        if (lane == 0) {
            float g = s + bg2v;
            gate[n] = g;
            int b = batch[n];
            if (b != curb) {
                atomicMax(&gmaxu[curb], fenc(lmax));
                lmax = -3.4e38f; curb = b;
            }
            lmax = fmaxf(lmax, g);
        }
    }
    if (lane == 0) atomicMax(&gmaxu[curb], fenc(lmax));
}

// ---------------- exp + per-graph denom (contiguous 4-node runs/thread) ----
__global__ __launch_bounds__(256) void expdenom_kernel(
    const float* __restrict__ gate, const int* __restrict__ batch,
    const unsigned* __restrict__ gmaxu, float* __restrict__ ealpha, float* __restrict__ denom)
{
    int tid = blockIdx.x * 256 + threadIdx.x;
    int i0 = tid * 4;
    if (i0 >= NN) return;
    int i1 = min(i0 + 4, NN);
    int curb = batch[i0];
    float m = fdec(gmaxu[curb]);
    float lsum = 0.f;
    for (int i = i0; i < i1; i++) {
        int b = batch[i];
        if (b != curb) {
            atomicAdd(&denom[curb], lsum);
            lsum = 0.f; curb = b; m = fdec(gmaxu[b]);
        }
        float ex = expf(gate[i] - m);
        ealpha[i] = ex;
        lsum += ex;
    }
    atomicAdd(&denom[curb], lsum);
}

// ---------------- pooled[g] = sum (e/denom) * h2[n] (batch sorted, vectorized) ----
__global__ __launch_bounds__(256) void pool_kernel(
    const ushort* __restrict__ h2, const float* __restrict__ ealpha,
    const float* __restrict__ denom, const int* __restrict__ batch,
    float* __restrict__ pooled)
{
    int t = threadIdx.x;
    int g = t >> 5, l = t & 31;
    int c = l * 8;
    int row0 = blockIdx.x * 128 + g * 16;
    if (row0 >= NN) return;
    int rend = min(row0 + 16, NN);
    float acc[8];
    #pragma unroll
    for (int q = 0; q < 8; q++) acc[q] = 0.f;
    int curg = batch[row0];
    for (int r = row0; r < rend; r++) {
        int gb = batch[r];
        if (gb != curg) {
            float inv = 1.0f / denom[curg];
            #pragma unroll
            for (int q = 0; q < 8; q++) atomicAdd(&pooled[curg * DL + c + q], acc[q] * inv);
            #pragma unroll
            for (int q = 0; q < 8; q++) acc[q] = 0.f;
            curg = gb;
        }
        float w = ealpha[r];
        uint4 v = *(const uint4*)&h2[(size_t)r * DL + c];
        accw8(acc, v, w);
    }
    float inv = 1.0f / denom[curg];
    #pragma unroll
    for (int q = 0; q < 8; q++) atomicAdd(&pooled[curg * DL + c + q], acc[q] * inv);
}

__global__ void head_kernel(
    const float* __restrict__ pooled, const float* __restrict__ Wgl,
    const float* __restrict__ bgl, float* __restrict__ out)
{
    int g = blockIdx.x;
    int lane = threadIdx.x;           // 64
    float s = 0.f;
    #pragma unroll
    for (int c = 0; c < 4; c++) {
        int d = c * 64 + lane;
        s += pooled[g * DL + d] * Wgl[d];
    }
    #pragma unroll
    for (int o = 32; o > 0; o >>= 1) s += __shfl_down(s, o, 64);
    if (lane == 0) out[g] = sigmoidf_(s + bgl[0]);
}

extern "C" void kernel_launch(void* const* d_in, const int* in_sizes, int n_in,
                              void* d_out, int out_size, void* d_ws, size_t ws_size,
                              hipStream_t stream)
{
    const int* x      = (const int*)d_in[0];
    const int* ei     = (const int*)d_in[1];
    const int* etype  = (const int*)d_in[2];
    const int* batch  = (const int*)d_in[3];
    const float* e0   = (const float*)d_in[4];
    const float* e1   = (const float*)d_in[5];
    const float* e2   = (const float*)d_in[6];
    const float* e3   = (const float*)d_in[7];
    const float* e4   = (const float*)d_in[8];
    const float* e5   = (const float*)d_in[9];
    const float* W1   = (const float*)d_in[10];
    const float* root1= (const float*)d_in[11];
    const float* b1   = (const float*)d_in[12];
    const float* W2   = (const float*)d_in[13];
    const float* root2= (const float*)d_in[14];
    const float* b2   = (const float*)d_in[15];
    const float* Wg1  = (const float*)d_in[16];
    const float* bg1  = (const float*)d_in[17];
    const float* gamma= (const float*)d_in[18];
    const float* beta = (const float*)d_in[19];
    const float* Wg2  = (const float*)d_in[20];
    const float* bg2  = (const float*)d_in[21];
    const float* Wgl  = (const float*)d_in[22];
    const float* bgl  = (const float*)d_in[23];
    float* out = (float*)d_out;

    const int* esrc_in = ei;          // edge_index[0]
    const int* edst_in = ei + EE;     // edge_index[1]

    char* ws = (char*)d_ws;
    size_t off = 0;
    auto alloc = [&](size_t b) -> char* {
        char* p = ws + off;
        off += (b + 255) & ~(size_t)255;
        return p;
    };
    // h2 only needs NN x DL now (layer-1 LUT restructure removed h0's 384-col
    // footprint) -> frees 12.8 MB so npc=4 hrc (102.4 MB) can fit.
    ushort* h2     = (ushort*)alloc((size_t)NN * DL * 2);    // 25.6 MB
    ushort* h1     = (ushort*)alloc((size_t)NN * DL * 2);    // 25.6 MB
    ushort* hacc   = (ushort*)alloc((size_t)NN * DL * 2);    // 25.6 MB bf16
    size_t zstart = off;                                     // ---- zeroed region ----
    int*      counts  = (int*)alloc((size_t)NN * RR * 4);
    float*    colsum  = (float*)alloc(DL * 4);
    float*    colsum2 = (float*)alloc(DL * 4);
    unsigned* gmaxu   = (unsigned*)alloc(GG * 4);
    float*    denom   = (float*)alloc(GG * 4);
    float*    pooled  = (float*)alloc((size_t)GG * DL * 4);
    size_t zbytes = off - zstart;                            // ---- end zeroed ----
    int*   offs    = (int*)alloc((size_t)NN * RR * 4);
    int*   cursors = (int*)alloc((size_t)NN * RR * 4);
    int2*  epk     = (int2*)alloc((size_t)EE * 8);           // packed (idx, weight)
    int*   blkSums = (int*)alloc(512);
    int*   blkOff  = (int*)alloc(512);
    float* mu      = (float*)alloc(DL * 4);
    float* aa      = (float*)alloc(DL * 4);
    float* gate    = (float*)alloc((size_t)NN * 4);
    float* ealpha  = (float*)alloc((size_t)NN * 4);
    ushort* Tlut   = (ushort*)alloc((size_t)NCR * 9 * DL * 2); // 230.4 KB LUT
    ushort* WbT2   = (ushort*)alloc((size_t)9 * DL * DL * 2);  // 1.18 MB
    ushort* WbTg   = (ushort*)alloc((size_t)1 * DL * DL * 2);  // 131 KB

    // hrc LAST (bf16): prefer 4-relation chunks (102.4 MB), else 2.
    int npc;
    ushort* hrc;
    {
        size_t need4 = ((size_t)NN * 4 * DL * 2 + 255) & ~(size_t)255;
        size_t need2 = ((size_t)NN * 2 * DL * 2 + 255) & ~(size_t)255;
        if (off + need4 <= ws_size)      { npc = 4; hrc = (ushort*)alloc((size_t)NN * 4 * DL * 2); }
        else if (off + need2 <= ws_size) { npc = 2; hrc = (ushort*)alloc((size_t)NN * 2 * DL * 2); }
        else return;   // fail loudly (wrong output) rather than corrupt
    }
    const int chc = npc * DL;

    ushort* hg1 = hrc;    // hrc dead after layer2's last gather

    hipMemsetAsync(ws + zstart, 0, zbytes, stream);

    // layer-1 LUT + layer-2/gate weight transposes
    lutbuild_kernel<<<NCR * 9, 256, 0, stream>>>(e0, e1, e2, e3, e4, e5, W1, root1, Tlut);
    count_kernel<<<(EE + 255) / 256, 256, 0, stream>>>(edst_in, etype, counts);
    {
        int tot2 = 9 * DL * DL;
        cvtT_kernel<<<(tot2 + 255) / 256, 256, 0, stream>>>(W2, root2, WbT2, RR, DL);
        int totg = 1 * DL * DL;
        cvtT_kernel<<<(totg + 255) / 256, 256, 0, stream>>>(nullptr, Wg1, WbTg, 0, DL);
    }

    const int M = NN * RR;
    const int NB = (M + SCAN_CHUNK - 1) / SCAN_CHUNK;   // 98
    scanA_kernel<<<NB, 256, 0, stream>>>(counts, M, blkSums);
    scanB_kernel<<<1, 64, 0, stream>>>(blkSums, NB, blkOff);
    scanC_kernel<<<NB, 256, 0, stream>>>(counts, M, blkOff, offs, cursors);
    scatter_kernel<<<(EE + 255) / 256, 256, 0, stream>>>(esrc_in, edst_in, etype, counts, cursors,
                                                          epk, chc, npc - 1);

    const int MT = (NN + 127) / 128;   // 391 M-tiles
    const dim3 GC(npc * 2, MT), G2(2, MT);
    const int ABLK = (NN + 7) / 8;

    // ---- layer 1 via LUT: per chunk, LUT-sum messages then gather ----
    for (int c0 = 0; c0 < RR; c0 += npc) {
        dim3 LG(512, npc);
        lutsum_kernel<<<LG, 256, 0, stream>>>(Tlut, x, hrc, c0, chc);
        gather_acc<<<ABLK, 256, 0, stream>>>(hrc, epk, offs, hacc, c0, c0 + npc, c0 == 0);
    }
    lutfin_kernel<<<512, 256, 0, stream>>>(Tlut, x, hacc, b1, h1);

    // ---- layer 2 (IN=256), GEMM-based ----
    for (int c0 = 0; c0 < RR; c0 += npc) {
        dense_gemm<DL, 0><<<GC, 256, 0, stream>>>(h1, WbT2 + (size_t)c0 * DL * DL, nullptr, nullptr, hrc, NN, chc);
        gather_acc<<<ABLK, 256, 0, stream>>>(hrc, epk, offs, hacc, c0, c0 + npc, c0 == 0);
    }
    dense_gemm<DL, 2><<<G2, 256, 0, stream>>>(h1, WbT2 + (size_t)8 * DL * DL, b2, hacc, h2, NN, DL);

    // ---- gate linear (no act; BN follows) ----
    dense_gemm<DL, 1><<<G2, 256, 0, stream>>>(h2, WbTg, bg1, nullptr, hg1, NN, DL);

    bnstats_kernel<<<256, 256, 0, stream>>>(hg1, colsum, colsum2);
    bnfinal_kernel<<<1, 256, 0, stream>>>(colsum, colsum2, gamma, mu, aa);
    gate_kernel<<<512, 256, 0, stream>>>(hg1, mu, aa, beta, Wg2, bg2, batch, gate, gmaxu);
    expdenom_kernel<<<((NN + 3) / 4 + 255) / 256, 256, 0, stream>>>(gate, batch, gmaxu, ealpha, denom);
    pool_kernel<<<(NN + 127) / 128, 256, 0, stream>>>(h2, ealpha, denom, batch, pooled);
    head_kernel<<<GG, 64, 0, stream>>>(pooled, Wgl, bgl, out);
}